// Round 1
// baseline (2787.333 us; speedup 1.0000x reference)
//
#include <hip/hip_runtime.h>

#define EPS_LN 1e-5f

// ---------------------------------------------------------------------------
// copy x -> H (float4 grid)
__global__ __launch_bounds__(256) void copy4_kernel(const float4* __restrict__ in,
                                                    float4* __restrict__ out, int n4) {
  int i = blockIdx.x * 256 + threadIdx.x;
  if (i < n4) out[i] = in[i];
}

// scatter mask_token into H rows listed in mn
__global__ __launch_bounds__(256) void mask_scatter_kernel(const int* __restrict__ mn,
                                                           const float* __restrict__ token,
                                                           float* __restrict__ H, int nmask) {
  int gid = blockIdx.x * 256 + threadIdx.x;
  if (gid >= nmask * 32) return;
  int i = gid >> 5;
  int c4 = (gid & 31) << 2;
  int r = mn[i];
  *(float4*)(H + (size_t)r * 128 + c4) = *(const float4*)(token + c4);
}

// ---------------------------------------------------------------------------
// Generic f32 GEMM: C[nrows, BN] = act( A1 @ W1^T (+ A2 @ W2^T) (+ bias) )
// W row-major [m, k]. BN = 16*TN = m. BM = 64 rows/block, 256 threads.
template <int TN>
__global__ __launch_bounds__(256) void gemm_kernel(
    const float* __restrict__ A1, const float* __restrict__ W1, int k1,
    const float* __restrict__ A2, const float* __restrict__ W2, int k2,
    const float* __restrict__ bias, int relu,
    float* __restrict__ C, int nrows) {
  constexpr int TM = 4;
  constexpr int BM = 64;
  constexpr int BN = 16 * TN;
  constexpr int KB = 16;
  __shared__ float As[KB][BM];
  __shared__ float Bs[KB][BN];

  const int tid = threadIdx.x;
  const int tx = tid & 15;   // col group
  const int ty = tid >> 4;   // row group
  const int row0 = blockIdx.x * BM;

  float acc[TM][TN];
#pragma unroll
  for (int i = 0; i < TM; ++i)
#pragma unroll
    for (int j = 0; j < TN; ++j) acc[i][j] = 0.f;

  for (int pass = 0; pass < 2; ++pass) {
    const float* A = pass ? A2 : A1;
    const float* W = pass ? W2 : W1;
    const int K = pass ? k2 : k1;
    if (A == nullptr) continue;  // uniform across block
    for (int k0 = 0; k0 < K; k0 += KB) {
      // stage A tile: BM x KB = 1024 floats, one float4/thread
      {
        int r = tid >> 2;
        int c4 = (tid & 3) << 2;
        int gr = row0 + r;
        float4 v = make_float4(0.f, 0.f, 0.f, 0.f);
        if (gr < nrows) v = *(const float4*)(A + (size_t)gr * K + k0 + c4);
        As[c4 + 0][r] = v.x;
        As[c4 + 1][r] = v.y;
        As[c4 + 2][r] = v.z;
        As[c4 + 3][r] = v.w;
      }
      // stage W tile: BN x KB floats
      for (int idx = tid; idx < BN * 4; idx += 256) {
        int col = idx >> 2;
        int c4 = (idx & 3) << 2;
        float4 v = *(const float4*)(W + (size_t)col * K + k0 + c4);
        Bs[c4 + 0][col] = v.x;
        Bs[c4 + 1][col] = v.y;
        Bs[c4 + 2][col] = v.z;
        Bs[c4 + 3][col] = v.w;
      }
      __syncthreads();
#pragma unroll
      for (int kk = 0; kk < KB; ++kk) {
        float a[TM], w[TN];
#pragma unroll
        for (int i = 0; i < TM; ++i) a[i] = As[kk][ty + i * 16];
#pragma unroll
        for (int j = 0; j < TN; ++j) w[j] = Bs[kk][tx + j * 16];
#pragma unroll
        for (int i = 0; i < TM; ++i)
#pragma unroll
          for (int j = 0; j < TN; ++j) acc[i][j] += a[i] * w[j];
      }
      __syncthreads();
    }
  }

#pragma unroll
  for (int i = 0; i < TM; ++i) {
    int r = row0 + ty + i * 16;
    if (r >= nrows) continue;
#pragma unroll
    for (int j = 0; j < TN; ++j) {
      int c = tx + j * 16;
      float v = acc[i][j];
      if (bias) v += bias[c];
      if (relu) v = fmaxf(v, 0.f);
      C[(size_t)r * BN + c] = v;
    }
  }
}

// ---------------------------------------------------------------------------
// segment_max via atomicMax on float bits (all messages >= 0, neigh pre-zeroed)
__global__ __launch_bounds__(256) void edge_max_kernel(
    const float* __restrict__ P, const int* __restrict__ src, const int* __restrict__ dst,
    const float* __restrict__ ew, int* __restrict__ neigh, int din, int cshift, int nE) {
  long long gid = (long long)blockIdx.x * 256 + threadIdx.x;
  int e = (int)(gid >> cshift);
  int c = ((int)gid & ((1 << cshift) - 1)) << 2;
  if (e >= nE || c >= din) return;
  int s = src[e];
  float w = ew[e];
  float4 pv = *(const float4*)(P + (size_t)s * din + c);
  int d = dst[e];
  size_t base = (size_t)d * din + c;
  atomicMax(neigh + base + 0, __float_as_int(pv.x * w));
  atomicMax(neigh + base + 1, __float_as_int(pv.y * w));
  atomicMax(neigh + base + 2, __float_as_int(pv.z * w));
  atomicMax(neigh + base + 3, __float_as_int(pv.w * w));
}

// ---------------------------------------------------------------------------
// z = H @ Wnp^T + bnp  (H: [n,64], Wnp: [16,64]) then LayerNorm over 16 ch
__global__ __launch_bounds__(256) void nodepred_ln_kernel(
    const float* __restrict__ H, const float* __restrict__ Wnp, const float* __restrict__ bnp,
    const float* __restrict__ g, const float* __restrict__ lb,
    float* __restrict__ out, int nrows) {
  __shared__ float hs[16][64];
  int tid = threadIdx.x;
  int row0 = blockIdx.x * 16;
  {
    int r = tid >> 4;
    int c4 = (tid & 15) << 2;
    int gr = row0 + r;
    float4 v = make_float4(0.f, 0.f, 0.f, 0.f);
    if (gr < nrows) v = *(const float4*)(H + (size_t)gr * 64 + c4);
    *(float4*)&hs[r][c4] = v;
  }
  __syncthreads();
  int r = tid >> 4, j = tid & 15;
  float z = bnp[j];
  const float* wrow = Wnp + j * 64;
#pragma unroll 8
  for (int k = 0; k < 64; ++k) z += hs[r][k] * wrow[k];
  float s = z, s2 = z * z;
#pragma unroll
  for (int m = 1; m < 16; m <<= 1) {
    s += __shfl_xor(s, m, 16);
    s2 += __shfl_xor(s2, m, 16);
  }
  float mu = s * (1.f / 16.f);
  float var = s2 * (1.f / 16.f) - mu * mu;
  float o = (z - mu) * rsqrtf(var + EPS_LN) * g[j] + lb[j];
  int gr = row0 + r;
  if (gr < nrows) out[(size_t)gr * 16 + j] = o;
}

// ---------------------------------------------------------------------------
// out1[i] = R[mn[i]], out2[i] = X[mn[i]]   (rows of 128)
__global__ __launch_bounds__(256) void gather_out_kernel(
    const int* __restrict__ mn, const float* __restrict__ R, const float* __restrict__ X,
    float* __restrict__ o1, float* __restrict__ o2, int nmask) {
  int gid = blockIdx.x * 256 + threadIdx.x;
  if (gid >= nmask * 32) return;
  int i = gid >> 5, c4 = (gid & 31) << 2;
  int r = mn[i];
  *(float4*)(o1 + (size_t)i * 128 + c4) = *(const float4*)(R + (size_t)r * 128 + c4);
  *(float4*)(o2 + (size_t)i * 128 + c4) = *(const float4*)(X + (size_t)r * 128 + c4);
}

// ---------------------------------------------------------------------------
static void launch_gemm(const float* A1, const float* W1, int k1,
                        const float* A2, const float* W2, int k2,
                        const float* bias, int relu, float* C, int m, int nrows,
                        hipStream_t s) {
  int blocks = (nrows + 63) / 64;
  switch (m) {
    case 128:
      gemm_kernel<8><<<blocks, 256, 0, s>>>(A1, W1, k1, A2, W2, k2, bias, relu, C, nrows);
      break;
    case 96:
      gemm_kernel<6><<<blocks, 256, 0, s>>>(A1, W1, k1, A2, W2, k2, bias, relu, C, nrows);
      break;
    case 64:
      gemm_kernel<4><<<blocks, 256, 0, s>>>(A1, W1, k1, A2, W2, k2, bias, relu, C, nrows);
      break;
  }
}

extern "C" void kernel_launch(void* const* d_in, const int* in_sizes, int n_in,
                              void* d_out, int out_size, void* d_ws, size_t ws_size,
                              hipStream_t stream) {
  const float* x = (const float*)d_in[0];
  const int* src = (const int*)d_in[1];
  const int* dst = (const int*)d_in[2];
  const float* ew = (const float*)d_in[3];
  const int* mn = (const int*)d_in[4];
  const float* token = (const float*)d_in[5];

  const float* W[25];
  for (int i = 0; i < 20; ++i) W[i] = (const float*)d_in[6 + i];
  const float* W_e2d = (const float*)d_in[26];
  const float* Wnp = (const float*)d_in[27];
  const float* bnp = (const float*)d_in[28];
  const float* ln_g = (const float*)d_in[29];
  const float* ln_b = (const float*)d_in[30];

  const int Nn = in_sizes[0] / 128;   // 50000
  const int E = in_sizes[1];          // 600000
  const int nmask = in_sizes[4];      // 10000

  float* bufA = (float*)d_ws;
  float* bufP = bufA + (size_t)Nn * 128;
  float* bufN = bufP + (size_t)Nn * 128;

  // h = x; h[mask_nodes] = token
  {
    int n4 = Nn * 128 / 4;
    copy4_kernel<<<(n4 + 255) / 256, 256, 0, stream>>>((const float4*)x, (float4*)bufA, n4);
    mask_scatter_kernel<<<(nmask * 32 + 255) / 256, 256, 0, stream>>>(mn, token, bufA, nmask);
  }

  auto run_sage = [&](const float* Wp, const float* bp, const float* Ws,
                      const float* Wn, const float* b, int din, int dout) {
    // p = relu(h @ Wp^T + bp)
    launch_gemm(bufA, Wp, din, nullptr, nullptr, 0, bp, 1, bufP, din, Nn, stream);
    // neigh = segment_max(p[src]*ew, dst) with zero-degree -> 0
    hipMemsetAsync(bufN, 0, (size_t)Nn * din * sizeof(float), stream);
    int cshift = (din > 64) ? 5 : 4;
    long long tot = (long long)E << cshift;
    int eblocks = (int)((tot + 255) / 256);
    edge_max_kernel<<<eblocks, 256, 0, stream>>>(bufP, src, dst, ew, (int*)bufN, din, cshift, E);
    // out = relu(h @ Ws^T + neigh @ Wn^T + b)
    launch_gemm(bufA, Ws, din, bufN, Wn, din, b, 1, bufP, dout, Nn, stream);
    float* t = bufA; bufA = bufP; bufP = t;
  };

  // encoder
  run_sage(W[0], W[1], W[2], W[3], W[4], 128, 96);    // enc0
  run_sage(W[5], W[6], W[7], W[8], W[9], 96, 64);     // enc1

  // node_pred + layernorm -> n_scores (out section 3)
  float* out_r = (float*)d_out;
  float* out_x = out_r + (size_t)nmask * 128;
  float* out_ns = out_x + (size_t)nmask * 128;
  nodepred_ln_kernel<<<(Nn + 15) / 16, 256, 0, stream>>>(bufA, Wnp, bnp, ln_g, ln_b, out_ns, Nn);

  // encoder_to_decoder: r = h2 @ W_e2d^T (no bias, no relu)
  launch_gemm(bufA, W_e2d, 64, nullptr, nullptr, 0, nullptr, 0, bufP, 64, Nn, stream);
  { float* t = bufA; bufA = bufP; bufP = t; }

  // decoder
  run_sage(W[10], W[11], W[12], W[13], W[14], 64, 96);   // dec0
  run_sage(W[15], W[16], W[17], W[18], W[19], 96, 128);  // dec1

  // outputs 1 & 2
  gather_out_kernel<<<(nmask * 32 + 255) / 256, 256, 0, stream>>>(mn, bufA, x, out_r, out_x, nmask);
}

// Round 2
// 700.698 us; speedup vs baseline: 3.9779x; 3.9779x over previous
//
#include <hip/hip_runtime.h>

#define EPS_LN 1e-5f

// ---------------------------------------------------------------------------
// copy x -> H (float4 grid)
__global__ __launch_bounds__(256) void copy4_kernel(const float4* __restrict__ in,
                                                    float4* __restrict__ out, int n4) {
  int i = blockIdx.x * 256 + threadIdx.x;
  if (i < n4) out[i] = in[i];
}

// scatter mask_token into H rows listed in mn
__global__ __launch_bounds__(256) void mask_scatter_kernel(const int* __restrict__ mn,
                                                           const float* __restrict__ token,
                                                           float* __restrict__ H, int nmask) {
  int gid = blockIdx.x * 256 + threadIdx.x;
  if (gid >= nmask * 32) return;
  int i = gid >> 5;
  int c4 = (gid & 31) << 2;
  int r = mn[i];
  *(float4*)(H + (size_t)r * 128 + c4) = *(const float4*)(token + c4);
}

// ---------------------------------------------------------------------------
// CSR build: histogram of dst
__global__ __launch_bounds__(256) void hist_kernel(const int* __restrict__ dst,
                                                   int* __restrict__ deg, int nE) {
  int e = blockIdx.x * 256 + threadIdx.x;
  if (e < nE) atomicAdd(deg + dst[e], 1);
}

// single-block exclusive scan of deg[n] -> off[n+1]
__global__ __launch_bounds__(1024) void scan_kernel(const int* __restrict__ deg,
                                                    int* __restrict__ off, int n) {
  __shared__ int ssum[1024];
  int tid = threadIdx.x;
  int per = (n + 1023) / 1024;
  int start = tid * per;
  int end = min(start + per, n);
  int s = 0;
  for (int i = start; i < end; ++i) s += deg[i];
  ssum[tid] = s;
  __syncthreads();
  for (int ofs = 1; ofs < 1024; ofs <<= 1) {
    int v = 0;
    if (tid >= ofs) v = ssum[tid - ofs];
    __syncthreads();
    if (tid >= ofs) ssum[tid] += v;
    __syncthreads();
  }
  int run = (tid == 0) ? 0 : ssum[tid - 1];
  for (int i = start; i < end; ++i) {
    off[i] = run;
    run += deg[i];
  }
  if (tid == 1023) off[n] = ssum[1023];
}

// scatter edges into dst-sorted order (store src and ew directly)
__global__ __launch_bounds__(256) void scatter_kernel(const int* __restrict__ src,
                                                      const int* __restrict__ dst,
                                                      const float* __restrict__ ew,
                                                      const int* __restrict__ off,
                                                      int* __restrict__ cur,
                                                      int* __restrict__ esrc,
                                                      float* __restrict__ eww, int nE) {
  int e = blockIdx.x * 256 + threadIdx.x;
  if (e >= nE) return;
  int d = dst[e];
  int pos = off[d] + atomicAdd(cur + d, 1);
  esrc[pos] = src[e];
  eww[pos] = ew[e];
}

// ---------------------------------------------------------------------------
// per-node segment max over CSR: din/4 lanes per node, one float4 per lane
__global__ __launch_bounds__(256) void neigh_csr_kernel(
    const float* __restrict__ P, const int* __restrict__ off,
    const int* __restrict__ esrc, const float* __restrict__ eww,
    float* __restrict__ neigh, int din, int lanes, int nN) {
  int gid = blockIdx.x * 256 + threadIdx.x;
  int v = gid / lanes;
  int c = (gid - v * lanes) << 2;
  if (v >= nN) return;
  int jlo = off[v], jhi = off[v + 1];
  float4 m = make_float4(0.f, 0.f, 0.f, 0.f);
  for (int j = jlo; j < jhi; ++j) {
    int s = esrc[j];
    float w = eww[j];
    float4 p = *(const float4*)(P + (size_t)s * din + c);
    m.x = fmaxf(m.x, p.x * w);
    m.y = fmaxf(m.y, p.y * w);
    m.z = fmaxf(m.z, p.z * w);
    m.w = fmaxf(m.w, p.w * w);
  }
  *(float4*)(neigh + (size_t)v * din + c) = m;
}

// ---------------------------------------------------------------------------
// Generic f32 GEMM: C[nrows, BN] = act( A1 @ W1^T (+ A2 @ W2^T) (+ bias) )
// W row-major [m, k]. BN = 16*TN = m. BM = 64 rows/block, 256 threads.
template <int TN>
__global__ __launch_bounds__(256) void gemm_kernel(
    const float* __restrict__ A1, const float* __restrict__ W1, int k1,
    const float* __restrict__ A2, const float* __restrict__ W2, int k2,
    const float* __restrict__ bias, int relu,
    float* __restrict__ C, int nrows) {
  constexpr int TM = 4;
  constexpr int BM = 64;
  constexpr int BN = 16 * TN;
  constexpr int KB = 16;
  __shared__ float As[KB][BM];
  __shared__ float Bs[KB][BN];

  const int tid = threadIdx.x;
  const int tx = tid & 15;   // col group
  const int ty = tid >> 4;   // row group
  const int row0 = blockIdx.x * BM;

  float acc[TM][TN];
#pragma unroll
  for (int i = 0; i < TM; ++i)
#pragma unroll
    for (int j = 0; j < TN; ++j) acc[i][j] = 0.f;

  for (int pass = 0; pass < 2; ++pass) {
    const float* A = pass ? A2 : A1;
    const float* W = pass ? W2 : W1;
    const int K = pass ? k2 : k1;
    if (A == nullptr) continue;  // uniform across block
    for (int k0 = 0; k0 < K; k0 += KB) {
      // stage A tile: BM x KB = 1024 floats, one float4/thread
      {
        int r = tid >> 2;
        int c4 = (tid & 3) << 2;
        int gr = row0 + r;
        float4 v = make_float4(0.f, 0.f, 0.f, 0.f);
        if (gr < nrows) v = *(const float4*)(A + (size_t)gr * K + k0 + c4);
        As[c4 + 0][r] = v.x;
        As[c4 + 1][r] = v.y;
        As[c4 + 2][r] = v.z;
        As[c4 + 3][r] = v.w;
      }
      // stage W tile: BN x KB floats
      for (int idx = tid; idx < BN * 4; idx += 256) {
        int col = idx >> 2;
        int c4 = (idx & 3) << 2;
        float4 v = *(const float4*)(W + (size_t)col * K + k0 + c4);
        Bs[c4 + 0][col] = v.x;
        Bs[c4 + 1][col] = v.y;
        Bs[c4 + 2][col] = v.z;
        Bs[c4 + 3][col] = v.w;
      }
      __syncthreads();
#pragma unroll
      for (int kk = 0; kk < KB; ++kk) {
        float a[TM], w[TN];
#pragma unroll
        for (int i = 0; i < TM; ++i) a[i] = As[kk][ty + i * 16];
#pragma unroll
        for (int j = 0; j < TN; ++j) w[j] = Bs[kk][tx + j * 16];
#pragma unroll
        for (int i = 0; i < TM; ++i)
#pragma unroll
          for (int j = 0; j < TN; ++j) acc[i][j] += a[i] * w[j];
      }
      __syncthreads();
    }
  }

#pragma unroll
  for (int i = 0; i < TM; ++i) {
    int r = row0 + ty + i * 16;
    if (r >= nrows) continue;
#pragma unroll
    for (int j = 0; j < TN; ++j) {
      int c = tx + j * 16;
      float v = acc[i][j];
      if (bias) v += bias[c];
      if (relu) v = fmaxf(v, 0.f);
      C[(size_t)r * BN + c] = v;
    }
  }
}

// ---------------------------------------------------------------------------
// z = H @ Wnp^T + bnp  (H: [n,64], Wnp: [16,64]) then LayerNorm over 16 ch
__global__ __launch_bounds__(256) void nodepred_ln_kernel(
    const float* __restrict__ H, const float* __restrict__ Wnp, const float* __restrict__ bnp,
    const float* __restrict__ g, const float* __restrict__ lb,
    float* __restrict__ out, int nrows) {
  __shared__ float hs[16][64];
  int tid = threadIdx.x;
  int row0 = blockIdx.x * 16;
  {
    int r = tid >> 4;
    int c4 = (tid & 15) << 2;
    int gr = row0 + r;
    float4 v = make_float4(0.f, 0.f, 0.f, 0.f);
    if (gr < nrows) v = *(const float4*)(H + (size_t)gr * 64 + c4);
    *(float4*)&hs[r][c4] = v;
  }
  __syncthreads();
  int r = tid >> 4, j = tid & 15;
  float z = bnp[j];
  const float* wrow = Wnp + j * 64;
#pragma unroll 8
  for (int k = 0; k < 64; ++k) z += hs[r][k] * wrow[k];
  float s = z, s2 = z * z;
#pragma unroll
  for (int m = 1; m < 16; m <<= 1) {
    s += __shfl_xor(s, m, 16);
    s2 += __shfl_xor(s2, m, 16);
  }
  float mu = s * (1.f / 16.f);
  float var = s2 * (1.f / 16.f) - mu * mu;
  float o = (z - mu) * rsqrtf(var + EPS_LN) * g[j] + lb[j];
  int gr = row0 + r;
  if (gr < nrows) out[(size_t)gr * 16 + j] = o;
}

// ---------------------------------------------------------------------------
// out1[i] = R[mn[i]], out2[i] = X[mn[i]]   (rows of 128)
__global__ __launch_bounds__(256) void gather_out_kernel(
    const int* __restrict__ mn, const float* __restrict__ R, const float* __restrict__ X,
    float* __restrict__ o1, float* __restrict__ o2, int nmask) {
  int gid = blockIdx.x * 256 + threadIdx.x;
  if (gid >= nmask * 32) return;
  int i = gid >> 5, c4 = (gid & 31) << 2;
  int r = mn[i];
  *(float4*)(o1 + (size_t)i * 128 + c4) = *(const float4*)(R + (size_t)r * 128 + c4);
  *(float4*)(o2 + (size_t)i * 128 + c4) = *(const float4*)(X + (size_t)r * 128 + c4);
}

// ---------------------------------------------------------------------------
static void launch_gemm(const float* A1, const float* W1, int k1,
                        const float* A2, const float* W2, int k2,
                        const float* bias, int relu, float* C, int m, int nrows,
                        hipStream_t s) {
  int blocks = (nrows + 63) / 64;
  switch (m) {
    case 128:
      gemm_kernel<8><<<blocks, 256, 0, s>>>(A1, W1, k1, A2, W2, k2, bias, relu, C, nrows);
      break;
    case 96:
      gemm_kernel<6><<<blocks, 256, 0, s>>>(A1, W1, k1, A2, W2, k2, bias, relu, C, nrows);
      break;
    case 64:
      gemm_kernel<4><<<blocks, 256, 0, s>>>(A1, W1, k1, A2, W2, k2, bias, relu, C, nrows);
      break;
  }
}

extern "C" void kernel_launch(void* const* d_in, const int* in_sizes, int n_in,
                              void* d_out, int out_size, void* d_ws, size_t ws_size,
                              hipStream_t stream) {
  const float* x = (const float*)d_in[0];
  const int* src = (const int*)d_in[1];
  const int* dst = (const int*)d_in[2];
  const float* ew = (const float*)d_in[3];
  const int* mn = (const int*)d_in[4];
  const float* token = (const float*)d_in[5];

  const float* W[25];
  for (int i = 0; i < 20; ++i) W[i] = (const float*)d_in[6 + i];
  const float* W_e2d = (const float*)d_in[26];
  const float* Wnp = (const float*)d_in[27];
  const float* bnp = (const float*)d_in[28];
  const float* ln_g = (const float*)d_in[29];
  const float* ln_b = (const float*)d_in[30];

  const int Nn = in_sizes[0] / 128;   // 50000
  const int E = in_sizes[1];          // 600000
  const int nmask = in_sizes[4];      // 10000

  // workspace layout
  float* bufA = (float*)d_ws;                      // N*128 f32
  float* bufP = bufA + (size_t)Nn * 128;           // N*128 f32
  float* bufN = bufP + (size_t)Nn * 128;           // N*128 f32
  int* deg = (int*)(bufN + (size_t)Nn * 128);      // N int
  int* cur = deg + Nn;                             // N int
  int* off = cur + Nn;                             // N+1 int
  int* esrc = off + Nn + 1;                        // E int
  float* eww = (float*)(esrc + E);                 // E f32

  // ---- CSR build (once; graph identical across layers) ----
  hipMemsetAsync(deg, 0, (size_t)Nn * 2 * sizeof(int), stream);  // deg + cur
  hist_kernel<<<(E + 255) / 256, 256, 0, stream>>>(dst, deg, E);
  scan_kernel<<<1, 1024, 0, stream>>>(deg, off, Nn);
  scatter_kernel<<<(E + 255) / 256, 256, 0, stream>>>(src, dst, ew, off, cur, esrc, eww, E);

  // h = x; h[mask_nodes] = token
  {
    int n4 = Nn * 128 / 4;
    copy4_kernel<<<(n4 + 255) / 256, 256, 0, stream>>>((const float4*)x, (float4*)bufA, n4);
    mask_scatter_kernel<<<(nmask * 32 + 255) / 256, 256, 0, stream>>>(mn, token, bufA, nmask);
  }

  auto run_sage = [&](const float* Wp, const float* bp, const float* Ws,
                      const float* Wn, const float* b, int din, int dout) {
    // p = relu(h @ Wp^T + bp)
    launch_gemm(bufA, Wp, din, nullptr, nullptr, 0, bp, 1, bufP, din, Nn, stream);
    // neigh = segment_max(p[src]*ew, dst); zero-degree rows -> 0
    int lanes = din >> 2;
    long long tot = (long long)Nn * lanes;
    int nblocks = (int)((tot + 255) / 256);
    neigh_csr_kernel<<<nblocks, 256, 0, stream>>>(bufP, off, esrc, eww, bufN, din, lanes, Nn);
    // out = relu(h @ Ws^T + neigh @ Wn^T + b)
    launch_gemm(bufA, Ws, din, bufN, Wn, din, b, 1, bufP, dout, Nn, stream);
    float* t = bufA; bufA = bufP; bufP = t;
  };

  // encoder
  run_sage(W[0], W[1], W[2], W[3], W[4], 128, 96);    // enc0
  run_sage(W[5], W[6], W[7], W[8], W[9], 96, 64);     // enc1

  // node_pred + layernorm -> n_scores (out section 3)
  float* out_r = (float*)d_out;
  float* out_x = out_r + (size_t)nmask * 128;
  float* out_ns = out_x + (size_t)nmask * 128;
  nodepred_ln_kernel<<<(Nn + 15) / 16, 256, 0, stream>>>(bufA, Wnp, bnp, ln_g, ln_b, out_ns, Nn);

  // encoder_to_decoder: r = h2 @ W_e2d^T (no bias, no relu)
  launch_gemm(bufA, W_e2d, 64, nullptr, nullptr, 0, nullptr, 0, bufP, 64, Nn, stream);
  { float* t = bufA; bufA = bufP; bufP = t; }

  // decoder
  run_sage(W[10], W[11], W[12], W[13], W[14], 64, 96);   // dec0
  run_sage(W[15], W[16], W[17], W[18], W[19], 96, 128);  // dec1

  // outputs 1 & 2
  gather_out_kernel<<<(nmask * 32 + 255) / 256, 256, 0, stream>>>(mn, bufA, x, out_r, out_x, nmask);
}

// Round 3
// 618.561 us; speedup vs baseline: 4.5062x; 1.1328x over previous
//
#include <hip/hip_runtime.h>

#define EPS_LN 1e-5f

// ---------------------------------------------------------------------------
// copy x -> H (float4 grid)
__global__ __launch_bounds__(256) void copy4_kernel(const float4* __restrict__ in,
                                                    float4* __restrict__ out, int n4) {
  int i = blockIdx.x * 256 + threadIdx.x;
  if (i < n4) out[i] = in[i];
}

// scatter mask_token into H rows listed in mn
__global__ __launch_bounds__(256) void mask_scatter_kernel(const int* __restrict__ mn,
                                                           const float* __restrict__ token,
                                                           float* __restrict__ H, int nmask) {
  int gid = blockIdx.x * 256 + threadIdx.x;
  if (gid >= nmask * 32) return;
  int i = gid >> 5;
  int c4 = (gid & 31) << 2;
  int r = mn[i];
  *(float4*)(H + (size_t)r * 128 + c4) = *(const float4*)(token + c4);
}

// ---------------------------------------------------------------------------
// CSR build: histogram of dst
__global__ __launch_bounds__(256) void hist_kernel(const int* __restrict__ dst,
                                                   int* __restrict__ deg, int nE) {
  int e = blockIdx.x * 256 + threadIdx.x;
  if (e < nE) atomicAdd(deg + dst[e], 1);
}

// ---- 3-phase parallel exclusive scan of deg[n] -> off[n+1] ----
#define SCAN_CHUNK 1024

// phase A: per-chunk totals
__global__ __launch_bounds__(256) void blocksum_kernel(const int* __restrict__ deg,
                                                       int* __restrict__ bsum, int n) {
  __shared__ int red[256];
  int base = blockIdx.x * SCAN_CHUNK;
  int tid = threadIdx.x;
  int s = 0;
#pragma unroll
  for (int t = 0; t < SCAN_CHUNK / 256; ++t) {
    int g = base + tid + t * 256;
    if (g < n) s += deg[g];
  }
  red[tid] = s;
  __syncthreads();
  for (int ofs = 128; ofs > 0; ofs >>= 1) {
    if (tid < ofs) red[tid] += red[tid + ofs];
    __syncthreads();
  }
  if (tid == 0) bsum[blockIdx.x] = red[0];
}

// phase B: 1-wave exclusive scan of nb (<64) chunk totals; also writes off[n]=total
__global__ __launch_bounds__(64) void bscan_kernel(const int* __restrict__ bsum,
                                                   int* __restrict__ bbase,
                                                   int* __restrict__ off_n, int nb) {
  int tid = threadIdx.x;
  int v = (tid < nb) ? bsum[tid] : 0;
  int incl = v;
#pragma unroll
  for (int ofs = 1; ofs < 64; ofs <<= 1) {
    int u = __shfl_up(incl, ofs, 64);
    if (tid >= ofs) incl += u;
  }
  if (tid < nb) bbase[tid] = incl - v;
  if (tid == nb - 1) off_n[0] = incl;
}

// phase C: per-chunk exclusive scan + chunk base
__global__ __launch_bounds__(256) void chunkscan_kernel(const int* __restrict__ deg,
                                                        const int* __restrict__ bbase,
                                                        int* __restrict__ off, int n) {
  __shared__ int part[256];
  int tid = threadIdx.x;
  int base = blockIdx.x * SCAN_CHUNK;
  int g0 = base + tid * 4;
  int loc[4];
  int s = 0;
#pragma unroll
  for (int j = 0; j < 4; ++j) {
    int g = g0 + j;
    int d = (g < n) ? deg[g] : 0;
    loc[j] = s;
    s += d;
  }
  part[tid] = s;
  __syncthreads();
  for (int ofs = 1; ofs < 256; ofs <<= 1) {
    int v = 0;
    if (tid >= ofs) v = part[tid - ofs];
    __syncthreads();
    if (tid >= ofs) part[tid] += v;
    __syncthreads();
  }
  int pre = (tid == 0) ? 0 : part[tid - 1];
  int b = bbase[blockIdx.x] + pre;
#pragma unroll
  for (int j = 0; j < 4; ++j) {
    int g = g0 + j;
    if (g < n) off[g] = b + loc[j];
  }
}

// scatter edges into dst-sorted order
__global__ __launch_bounds__(256) void scatter_kernel(const int* __restrict__ src,
                                                      const int* __restrict__ dst,
                                                      const float* __restrict__ ew,
                                                      const int* __restrict__ off,
                                                      int* __restrict__ cur,
                                                      int* __restrict__ esrc,
                                                      float* __restrict__ eww, int nE) {
  int e = blockIdx.x * 256 + threadIdx.x;
  if (e >= nE) return;
  int d = dst[e];
  int pos = off[d] + atomicAdd(cur + d, 1);
  esrc[pos] = src[e];
  eww[pos] = ew[e];
}

// ---------------------------------------------------------------------------
// per-node segment max over CSR: din/4 lanes per node, one float4 per lane
__global__ __launch_bounds__(256) void neigh_csr_kernel(
    const float* __restrict__ P, const int* __restrict__ off,
    const int* __restrict__ esrc, const float* __restrict__ eww,
    float* __restrict__ neigh, int din, int lanes, int nN) {
  int gid = blockIdx.x * 256 + threadIdx.x;
  int v = gid / lanes;
  int c = (gid - v * lanes) << 2;
  if (v >= nN) return;
  int jlo = off[v], jhi = off[v + 1];
  float4 m = make_float4(0.f, 0.f, 0.f, 0.f);
  for (int j = jlo; j < jhi; ++j) {
    int s = esrc[j];
    float w = eww[j];
    float4 p = *(const float4*)(P + (size_t)s * din + c);
    m.x = fmaxf(m.x, p.x * w);
    m.y = fmaxf(m.y, p.y * w);
    m.z = fmaxf(m.z, p.z * w);
    m.w = fmaxf(m.w, p.w * w);
  }
  *(float4*)(neigh + (size_t)v * din + c) = m;
}

// ---------------------------------------------------------------------------
// small weight-combine: C[M][N] = A[M][K] @ B[K][N]  (row-major, tiny)
__global__ __launch_bounds__(256) void matmul_small_kernel(const float* __restrict__ A,
                                                           const float* __restrict__ B,
                                                           float* __restrict__ C,
                                                           int M, int K, int N) {
  int idx = blockIdx.x * 256 + threadIdx.x;
  if (idx >= M * N) return;
  int o = idx / N, i = idx - o * N;
  float s = 0.f;
  for (int k = 0; k < K; ++k) s += A[o * K + k] * B[k * N + i];
  C[idx] = s;
}

// ---------------------------------------------------------------------------
// Generic f32 GEMM: C[nrows, BN] = act( A1 @ W1^T (+ A2 @ W2^T) (+ bias) )
// W row-major [BN, K]. BM = 128 rows/block, 256 threads, TM=8 rows/thread,
// TN cols/thread (contiguous), BN = 16*TN.
template <int TN>
__global__ __launch_bounds__(256) void gemm_kernel(
    const float* __restrict__ A1, const float* __restrict__ W1, int k1,
    const float* __restrict__ A2, const float* __restrict__ W2, int k2,
    const float* __restrict__ bias, int relu,
    float* __restrict__ C, int nrows) {
  constexpr int TM = 8;
  constexpr int BM = 128;
  constexpr int BN = 16 * TN;
  constexpr int KB = 16;
  __shared__ float As[KB][BM];
  __shared__ float Bs[KB][BN];

  const int tid = threadIdx.x;
  const int tx = tid & 15;   // col group: owns cols tx*TN .. tx*TN+TN-1
  const int ty = tid >> 4;   // row group: owns rows ty*TM .. ty*TM+TM-1
  const int row0 = blockIdx.x * BM;

  float acc[TM][TN];
#pragma unroll
  for (int i = 0; i < TM; ++i)
#pragma unroll
    for (int j = 0; j < TN; ++j) acc[i][j] = 0.f;

  for (int pass = 0; pass < 2; ++pass) {
    const float* A = pass ? A2 : A1;
    const float* W = pass ? W2 : W1;
    const int K = pass ? k2 : k1;
    if (A == nullptr) continue;  // uniform across block
    for (int k0 = 0; k0 < K; k0 += KB) {
      // stage A tile: BM x KB = 512 float4, 2 per thread
#pragma unroll
      for (int t = 0; t < 2; ++t) {
        int idx = tid + t * 256;
        int r = idx >> 2;
        int c4 = (idx & 3) << 2;
        int gr = row0 + r;
        float4 v = make_float4(0.f, 0.f, 0.f, 0.f);
        if (gr < nrows) v = *(const float4*)(A + (size_t)gr * K + k0 + c4);
        As[c4 + 0][r] = v.x;
        As[c4 + 1][r] = v.y;
        As[c4 + 2][r] = v.z;
        As[c4 + 3][r] = v.w;
      }
      // stage W tile: BN x KB floats
      for (int idx = tid; idx < BN * 4; idx += 256) {
        int col = idx >> 2;
        int c4 = (idx & 3) << 2;
        float4 v = *(const float4*)(W + (size_t)col * K + k0 + c4);
        Bs[c4 + 0][col] = v.x;
        Bs[c4 + 1][col] = v.y;
        Bs[c4 + 2][col] = v.z;
        Bs[c4 + 3][col] = v.w;
      }
      __syncthreads();
#pragma unroll
      for (int kk = 0; kk < KB; ++kk) {
        float a[TM], w[TN];
#pragma unroll
        for (int i = 0; i < TM; ++i) a[i] = As[kk][ty * TM + i];
#pragma unroll
        for (int j = 0; j < TN; ++j) w[j] = Bs[kk][tx * TN + j];
#pragma unroll
        for (int i = 0; i < TM; ++i)
#pragma unroll
          for (int j = 0; j < TN; ++j) acc[i][j] += a[i] * w[j];
      }
      __syncthreads();
    }
  }

#pragma unroll
  for (int i = 0; i < TM; ++i) {
    int r = row0 + ty * TM + i;
    if (r >= nrows) continue;
#pragma unroll
    for (int j = 0; j < TN; ++j) {
      int c = tx * TN + j;
      float v = acc[i][j];
      if (bias) v += bias[c];
      if (relu) v = fmaxf(v, 0.f);
      C[(size_t)r * BN + c] = v;
    }
  }
}

// ---------------------------------------------------------------------------
// z = H @ Wnp^T + bnp  (H: [n,64], Wnp: [16,64]) then LayerNorm over 16 ch
__global__ __launch_bounds__(256) void nodepred_ln_kernel(
    const float* __restrict__ H, const float* __restrict__ Wnp, const float* __restrict__ bnp,
    const float* __restrict__ g, const float* __restrict__ lb,
    float* __restrict__ out, int nrows) {
  __shared__ float hs[16][64];
  int tid = threadIdx.x;
  int row0 = blockIdx.x * 16;
  {
    int r = tid >> 4;
    int c4 = (tid & 15) << 2;
    int gr = row0 + r;
    float4 v = make_float4(0.f, 0.f, 0.f, 0.f);
    if (gr < nrows) v = *(const float4*)(H + (size_t)gr * 64 + c4);
    *(float4*)&hs[r][c4] = v;
  }
  __syncthreads();
  int r = tid >> 4, j = tid & 15;
  float z = bnp[j];
  const float* wrow = Wnp + j * 64;
#pragma unroll 8
  for (int k = 0; k < 64; ++k) z += hs[r][k] * wrow[k];
  float s = z, s2 = z * z;
#pragma unroll
  for (int m = 1; m < 16; m <<= 1) {
    s += __shfl_xor(s, m, 16);
    s2 += __shfl_xor(s2, m, 16);
  }
  float mu = s * (1.f / 16.f);
  float var = s2 * (1.f / 16.f) - mu * mu;
  float o = (z - mu) * rsqrtf(var + EPS_LN) * g[j] + lb[j];
  int gr = row0 + r;
  if (gr < nrows) out[(size_t)gr * 16 + j] = o;
}

// ---------------------------------------------------------------------------
// out1[i] = R[mn[i]], out2[i] = X[mn[i]]   (rows of 128)
__global__ __launch_bounds__(256) void gather_out_kernel(
    const int* __restrict__ mn, const float* __restrict__ R, const float* __restrict__ X,
    float* __restrict__ o1, float* __restrict__ o2, int nmask) {
  int gid = blockIdx.x * 256 + threadIdx.x;
  if (gid >= nmask * 32) return;
  int i = gid >> 5, c4 = (gid & 31) << 2;
  int r = mn[i];
  *(float4*)(o1 + (size_t)i * 128 + c4) = *(const float4*)(R + (size_t)r * 128 + c4);
  *(float4*)(o2 + (size_t)i * 128 + c4) = *(const float4*)(X + (size_t)r * 128 + c4);
}

// ---------------------------------------------------------------------------
static void launch_gemm(const float* A1, const float* W1, int k1,
                        const float* A2, const float* W2, int k2,
                        const float* bias, int relu, float* C, int m, int nrows,
                        hipStream_t s) {
  int blocks = (nrows + 127) / 128;
  switch (m) {
    case 128:
      gemm_kernel<8><<<blocks, 256, 0, s>>>(A1, W1, k1, A2, W2, k2, bias, relu, C, nrows);
      break;
    case 96:
      gemm_kernel<6><<<blocks, 256, 0, s>>>(A1, W1, k1, A2, W2, k2, bias, relu, C, nrows);
      break;
    case 64:
      gemm_kernel<4><<<blocks, 256, 0, s>>>(A1, W1, k1, A2, W2, k2, bias, relu, C, nrows);
      break;
  }
}

extern "C" void kernel_launch(void* const* d_in, const int* in_sizes, int n_in,
                              void* d_out, int out_size, void* d_ws, size_t ws_size,
                              hipStream_t stream) {
  const float* x = (const float*)d_in[0];
  const int* src = (const int*)d_in[1];
  const int* dst = (const int*)d_in[2];
  const float* ew = (const float*)d_in[3];
  const int* mn = (const int*)d_in[4];
  const float* token = (const float*)d_in[5];

  const float* W[25];
  for (int i = 0; i < 20; ++i) W[i] = (const float*)d_in[6 + i];
  const float* W_e2d = (const float*)d_in[26];
  const float* Wnp = (const float*)d_in[27];
  const float* bnp = (const float*)d_in[28];
  const float* ln_g = (const float*)d_in[29];
  const float* ln_b = (const float*)d_in[30];

  const int Nn = in_sizes[0] / 128;   // 50000
  const int E = in_sizes[1];          // 600000
  const int nmask = in_sizes[4];      // 10000
  const int nb = (Nn + SCAN_CHUNK - 1) / SCAN_CHUNK;  // 49

  // workspace layout
  float* bufA = (float*)d_ws;                      // N*128 f32
  float* bufP = bufA + (size_t)Nn * 128;           // N*128 f32
  float* bufN = bufP + (size_t)Nn * 128;           // N*128 f32
  int* deg = (int*)(bufN + (size_t)Nn * 128);      // N int
  int* cur = deg + Nn;                             // N int
  int* off = cur + Nn;                             // N+1 int
  int* esrc = off + Nn + 1;                        // E int
  float* eww = (float*)(esrc + E);                 // E f32
  int* bsum = (int*)(eww + E);                     // nb int
  int* bbase = bsum + 64;                          // nb int
  float* WpP = (float*)(bbase + 64);               // 64*64 f32 (dec0 Wp @ W_e2d)
  float* WsP = WpP + 64 * 64;                      // 96*64 f32 (dec0 Ws @ W_e2d)

  // ---- fold encoder_to_decoder into dec0 weights (tiny) ----
  matmul_small_kernel<<<(64 * 64 + 255) / 256, 256, 0, stream>>>(W[10], W_e2d, WpP, 64, 64, 64);
  matmul_small_kernel<<<(96 * 64 + 255) / 256, 256, 0, stream>>>(W[12], W_e2d, WsP, 96, 64, 64);

  // ---- CSR build (once; graph identical across layers) ----
  hipMemsetAsync(deg, 0, (size_t)Nn * 2 * sizeof(int), stream);  // deg + cur
  hist_kernel<<<(E + 255) / 256, 256, 0, stream>>>(dst, deg, E);
  blocksum_kernel<<<nb, 256, 0, stream>>>(deg, bsum, Nn);
  bscan_kernel<<<1, 64, 0, stream>>>(bsum, bbase, off + Nn, nb);
  chunkscan_kernel<<<nb, 256, 0, stream>>>(deg, bbase, off, Nn);
  scatter_kernel<<<(E + 255) / 256, 256, 0, stream>>>(src, dst, ew, off, cur, esrc, eww, E);

  // h = x; h[mask_nodes] = token
  {
    int n4 = Nn * 128 / 4;
    copy4_kernel<<<(n4 + 255) / 256, 256, 0, stream>>>((const float4*)x, (float4*)bufA, n4);
    mask_scatter_kernel<<<(nmask * 32 + 255) / 256, 256, 0, stream>>>(mn, token, bufA, nmask);
  }

  auto run_sage = [&](const float* Wp, const float* bp, const float* Ws,
                      const float* Wn, const float* b, int din, int dout) {
    // p = relu(h @ Wp^T + bp)
    launch_gemm(bufA, Wp, din, nullptr, nullptr, 0, bp, 1, bufP, din, Nn, stream);
    // neigh = segment_max(p[src]*ew, dst); zero-degree rows -> 0
    int lanes = din >> 2;
    long long tot = (long long)Nn * lanes;
    int nblocks = (int)((tot + 255) / 256);
    neigh_csr_kernel<<<nblocks, 256, 0, stream>>>(bufP, off, esrc, eww, bufN, din, lanes, Nn);
    // out = relu(h @ Ws^T + neigh @ Wn^T + b)
    launch_gemm(bufA, Ws, din, bufN, Wn, din, b, 1, bufP, dout, Nn, stream);
    float* t = bufA; bufA = bufP; bufP = t;
  };

  // encoder
  run_sage(W[0], W[1], W[2], W[3], W[4], 128, 96);    // enc0
  run_sage(W[5], W[6], W[7], W[8], W[9], 96, 64);     // enc1

  // node_pred + layernorm -> n_scores (out section 3)
  float* out_r = (float*)d_out;
  float* out_x = out_r + (size_t)nmask * 128;
  float* out_ns = out_x + (size_t)nmask * 128;
  nodepred_ln_kernel<<<(Nn + 15) / 16, 256, 0, stream>>>(bufA, Wnp, bnp, ln_g, ln_b, out_ns, Nn);

  // decoder (e2d folded into dec0 weights: r = h2@W_e2d^T absorbed)
  run_sage(WpP, W[11], WsP, W[13], W[14], 64, 96);       // dec0 (+e2d)
  run_sage(W[15], W[16], W[17], W[18], W[19], 96, 128);  // dec1

  // outputs 1 & 2
  gather_out_kernel<<<(nmask * 32 + 255) / 256, 256, 0, stream>>>(mn, bufA, x, out_r, out_x, nmask);
}

// Round 4
// 564.507 us; speedup vs baseline: 4.9376x; 1.0958x over previous
//
#include <hip/hip_runtime.h>

#define EPS_LN 1e-5f

// ---------------------------------------------------------------------------
// copy x -> H (float4 grid)
__global__ __launch_bounds__(256) void copy4_kernel(const float4* __restrict__ in,
                                                    float4* __restrict__ out, int n4) {
  int i = blockIdx.x * 256 + threadIdx.x;
  if (i < n4) out[i] = in[i];
}

// scatter mask_token into H rows listed in mn
__global__ __launch_bounds__(256) void mask_scatter_kernel(const int* __restrict__ mn,
                                                           const float* __restrict__ token,
                                                           float* __restrict__ H, int nmask) {
  int gid = blockIdx.x * 256 + threadIdx.x;
  if (gid >= nmask * 32) return;
  int i = gid >> 5;
  int c4 = (gid & 31) << 2;
  int r = mn[i];
  *(float4*)(H + (size_t)r * 128 + c4) = *(const float4*)(token + c4);
}

// ---------------------------------------------------------------------------
// CSR build: histogram of dst
__global__ __launch_bounds__(256) void hist_kernel(const int* __restrict__ dst,
                                                   int* __restrict__ deg, int nE) {
  int e = blockIdx.x * 256 + threadIdx.x;
  if (e < nE) atomicAdd(deg + dst[e], 1);
}

// ---- 3-phase parallel exclusive scan of deg[n] -> off[n+1] ----
#define SCAN_CHUNK 1024

__global__ __launch_bounds__(256) void blocksum_kernel(const int* __restrict__ deg,
                                                       int* __restrict__ bsum, int n) {
  __shared__ int red[256];
  int base = blockIdx.x * SCAN_CHUNK;
  int tid = threadIdx.x;
  int s = 0;
#pragma unroll
  for (int t = 0; t < SCAN_CHUNK / 256; ++t) {
    int g = base + tid + t * 256;
    if (g < n) s += deg[g];
  }
  red[tid] = s;
  __syncthreads();
  for (int ofs = 128; ofs > 0; ofs >>= 1) {
    if (tid < ofs) red[tid] += red[tid + ofs];
    __syncthreads();
  }
  if (tid == 0) bsum[blockIdx.x] = red[0];
}

__global__ __launch_bounds__(64) void bscan_kernel(const int* __restrict__ bsum,
                                                   int* __restrict__ bbase,
                                                   int* __restrict__ off_n, int nb) {
  int tid = threadIdx.x;
  int v = (tid < nb) ? bsum[tid] : 0;
  int incl = v;
#pragma unroll
  for (int ofs = 1; ofs < 64; ofs <<= 1) {
    int u = __shfl_up(incl, ofs, 64);
    if (tid >= ofs) incl += u;
  }
  if (tid < nb) bbase[tid] = incl - v;
  if (tid == nb - 1) off_n[0] = incl;
}

__global__ __launch_bounds__(256) void chunkscan_kernel(const int* __restrict__ deg,
                                                        const int* __restrict__ bbase,
                                                        int* __restrict__ off, int n) {
  __shared__ int part[256];
  int tid = threadIdx.x;
  int base = blockIdx.x * SCAN_CHUNK;
  int g0 = base + tid * 4;
  int loc[4];
  int s = 0;
#pragma unroll
  for (int j = 0; j < 4; ++j) {
    int g = g0 + j;
    int d = (g < n) ? deg[g] : 0;
    loc[j] = s;
    s += d;
  }
  part[tid] = s;
  __syncthreads();
  for (int ofs = 1; ofs < 256; ofs <<= 1) {
    int v = 0;
    if (tid >= ofs) v = part[tid - ofs];
    __syncthreads();
    if (tid >= ofs) part[tid] += v;
    __syncthreads();
  }
  int pre = (tid == 0) ? 0 : part[tid - 1];
  int b = bbase[blockIdx.x] + pre;
#pragma unroll
  for (int j = 0; j < 4; ++j) {
    int g = g0 + j;
    if (g < n) off[g] = b + loc[j];
  }
}

// scatter edges into dst-sorted order
__global__ __launch_bounds__(256) void scatter_kernel(const int* __restrict__ src,
                                                      const int* __restrict__ dst,
                                                      const float* __restrict__ ew,
                                                      const int* __restrict__ off,
                                                      int* __restrict__ cur,
                                                      int* __restrict__ esrc,
                                                      float* __restrict__ eww, int nE) {
  int e = blockIdx.x * 256 + threadIdx.x;
  if (e >= nE) return;
  int d = dst[e];
  int pos = off[d] + atomicAdd(cur + d, 1);
  esrc[pos] = src[e];
  eww[pos] = ew[e];
}

// ---------------------------------------------------------------------------
// per-node segment max over CSR: din/4 lanes per node, one float4 per lane
__global__ __launch_bounds__(256) void neigh_csr_kernel(
    const float* __restrict__ P, const int* __restrict__ off,
    const int* __restrict__ esrc, const float* __restrict__ eww,
    float* __restrict__ neigh, int din, int lanes, int nN) {
  int gid = blockIdx.x * 256 + threadIdx.x;
  int v = gid / lanes;
  int c = (gid - v * lanes) << 2;
  if (v >= nN) return;
  int jlo = off[v], jhi = off[v + 1];
  float4 m = make_float4(0.f, 0.f, 0.f, 0.f);
  for (int j = jlo; j < jhi; ++j) {
    int s = esrc[j];
    float w = eww[j];
    float4 p = *(const float4*)(P + (size_t)s * din + c);
    m.x = fmaxf(m.x, p.x * w);
    m.y = fmaxf(m.y, p.y * w);
    m.z = fmaxf(m.z, p.z * w);
    m.w = fmaxf(m.w, p.w * w);
  }
  *(float4*)(neigh + (size_t)v * din + c) = m;
}

// ---------------------------------------------------------------------------
// small weight-combine: C[M][N] = A[M][K] @ B[K][N]  (row-major, tiny)
__global__ __launch_bounds__(256) void matmul_small_kernel(const float* __restrict__ A,
                                                           const float* __restrict__ B,
                                                           float* __restrict__ C,
                                                           int M, int K, int N) {
  int idx = blockIdx.x * 256 + threadIdx.x;
  if (idx >= M * N) return;
  int o = idx / N, i = idx - o * N;
  float s = 0.f;
  for (int k = 0; k < K; ++k) s += A[o * K + k] * B[k * N + i];
  C[idx] = s;
}

// ---------------------------------------------------------------------------
// Generic f32 GEMM: C[nrows, BN] = act( A1 @ W1^T (+ A2 @ W2^T) (+ bias) )
// W row-major [BN, K], K in {64,96,128}. BM=64 rows/block, 256 threads.
// Thread (ty=tid>>4, tx=tid&15): rows ty*4..ty*4+3 (contiguous, float4 LDS read),
// cols tx*2 + 32p for p<TN/2 (pair-interleaved, float2 LDS reads, conflict-free).
template <int TN>
__global__ __launch_bounds__(256) void gemm_kernel(
    const float* __restrict__ A1, const float* __restrict__ W1, int k1,
    const float* __restrict__ A2, const float* __restrict__ W2, int k2,
    const float* __restrict__ bias, int relu,
    float* __restrict__ C, int nrows) {
  constexpr int TM = 4;
  constexpr int BM = 64;
  constexpr int BN = 16 * TN;
  constexpr int KB = 32;
  constexpr int LDA = BM + 4;   // padded pitch (words)
  constexpr int LDB = BN + 4;
  __shared__ float As[KB * LDA];
  __shared__ float Bs[KB * LDB];

  const int tid = threadIdx.x;
  const int tx = tid & 15;
  const int ty = tid >> 4;
  const int row0 = blockIdx.x * BM;

  float acc[TM][TN];
#pragma unroll
  for (int i = 0; i < TM; ++i)
#pragma unroll
    for (int j = 0; j < TN; ++j) acc[i][j] = 0.f;

  for (int pass = 0; pass < 2; ++pass) {
    const float* A = pass ? A2 : A1;
    const float* W = pass ? W2 : W1;
    const int K = pass ? k2 : k1;
    if (A == nullptr) continue;  // uniform across block
    for (int k0 = 0; k0 < K; k0 += KB) {
      // stage A tile: BM x KB = 512 float4, 2 per thread (coalesced 128B rows)
#pragma unroll
      for (int t = 0; t < 2; ++t) {
        int idx = tid + t * 256;       // 0..511
        int r = idx >> 3;              // 0..63
        int c4 = (idx & 7) << 2;       // 0,4,..,28
        int gr = row0 + r;
        float4 v = make_float4(0.f, 0.f, 0.f, 0.f);
        if (gr < nrows) v = *(const float4*)(A + (size_t)gr * K + k0 + c4);
        As[(c4 + 0) * LDA + r] = v.x;
        As[(c4 + 1) * LDA + r] = v.y;
        As[(c4 + 2) * LDA + r] = v.z;
        As[(c4 + 3) * LDA + r] = v.w;
      }
      // stage W tile: BN x KB = 128*TN float4, TN/2 per thread
#pragma unroll
      for (int t = 0; t < TN / 2; ++t) {
        int idx = tid + t * 256;
        int col = idx >> 3;
        int c4 = (idx & 7) << 2;
        float4 v = *(const float4*)(W + (size_t)col * K + k0 + c4);
        Bs[(c4 + 0) * LDB + col] = v.x;
        Bs[(c4 + 1) * LDB + col] = v.y;
        Bs[(c4 + 2) * LDB + col] = v.z;
        Bs[(c4 + 3) * LDB + col] = v.w;
      }
      __syncthreads();
#pragma unroll 8
      for (int kk = 0; kk < KB; ++kk) {
        float a[TM], w[TN];
        *(float4*)a = *(const float4*)&As[kk * LDA + ty * 4];
#pragma unroll
        for (int p = 0; p < TN / 2; ++p)
          *(float2*)&w[p * 2] = *(const float2*)&Bs[kk * LDB + tx * 2 + 32 * p];
#pragma unroll
        for (int i = 0; i < TM; ++i)
#pragma unroll
          for (int j = 0; j < TN; ++j) acc[i][j] += a[i] * w[j];
      }
      __syncthreads();
    }
  }

#pragma unroll
  for (int i = 0; i < TM; ++i) {
    int r = row0 + ty * 4 + i;
    if (r >= nrows) continue;
#pragma unroll
    for (int p = 0; p < TN / 2; ++p) {
      int c = tx * 2 + 32 * p;
      float2 v = make_float2(acc[i][2 * p], acc[i][2 * p + 1]);
      if (bias) {
        v.x += bias[c];
        v.y += bias[c + 1];
      }
      if (relu) {
        v.x = fmaxf(v.x, 0.f);
        v.y = fmaxf(v.y, 0.f);
      }
      *(float2*)(C + (size_t)r * BN + c) = v;
    }
  }
}

// ---------------------------------------------------------------------------
// z = H @ Wnp^T + bnp  (H: [n,64], Wnp: [16,64]) then LayerNorm over 16 ch
__global__ __launch_bounds__(256) void nodepred_ln_kernel(
    const float* __restrict__ H, const float* __restrict__ Wnp, const float* __restrict__ bnp,
    const float* __restrict__ g, const float* __restrict__ lb,
    float* __restrict__ out, int nrows) {
  __shared__ float hs[16][64];
  int tid = threadIdx.x;
  int row0 = blockIdx.x * 16;
  {
    int r = tid >> 4;
    int c4 = (tid & 15) << 2;
    int gr = row0 + r;
    float4 v = make_float4(0.f, 0.f, 0.f, 0.f);
    if (gr < nrows) v = *(const float4*)(H + (size_t)gr * 64 + c4);
    *(float4*)&hs[r][c4] = v;
  }
  __syncthreads();
  int r = tid >> 4, j = tid & 15;
  float z = bnp[j];
  const float* wrow = Wnp + j * 64;
#pragma unroll 8
  for (int k = 0; k < 64; ++k) z += hs[r][k] * wrow[k];
  float s = z, s2 = z * z;
#pragma unroll
  for (int m = 1; m < 16; m <<= 1) {
    s += __shfl_xor(s, m, 16);
    s2 += __shfl_xor(s2, m, 16);
  }
  float mu = s * (1.f / 16.f);
  float var = s2 * (1.f / 16.f) - mu * mu;
  float o = (z - mu) * rsqrtf(var + EPS_LN) * g[j] + lb[j];
  int gr = row0 + r;
  if (gr < nrows) out[(size_t)gr * 16 + j] = o;
}

// ---------------------------------------------------------------------------
// out1[i] = R[mn[i]], out2[i] = X[mn[i]]   (rows of 128)
__global__ __launch_bounds__(256) void gather_out_kernel(
    const int* __restrict__ mn, const float* __restrict__ R, const float* __restrict__ X,
    float* __restrict__ o1, float* __restrict__ o2, int nmask) {
  int gid = blockIdx.x * 256 + threadIdx.x;
  if (gid >= nmask * 32) return;
  int i = gid >> 5, c4 = (gid & 31) << 2;
  int r = mn[i];
  *(float4*)(o1 + (size_t)i * 128 + c4) = *(const float4*)(R + (size_t)r * 128 + c4);
  *(float4*)(o2 + (size_t)i * 128 + c4) = *(const float4*)(X + (size_t)r * 128 + c4);
}

// ---------------------------------------------------------------------------
static void launch_gemm(const float* A1, const float* W1, int k1,
                        const float* A2, const float* W2, int k2,
                        const float* bias, int relu, float* C, int m, int nrows,
                        hipStream_t s) {
  int blocks = (nrows + 63) / 64;
  switch (m) {
    case 128:
      gemm_kernel<8><<<blocks, 256, 0, s>>>(A1, W1, k1, A2, W2, k2, bias, relu, C, nrows);
      break;
    case 96:
      gemm_kernel<6><<<blocks, 256, 0, s>>>(A1, W1, k1, A2, W2, k2, bias, relu, C, nrows);
      break;
    case 64:
      gemm_kernel<4><<<blocks, 256, 0, s>>>(A1, W1, k1, A2, W2, k2, bias, relu, C, nrows);
      break;
  }
}

extern "C" void kernel_launch(void* const* d_in, const int* in_sizes, int n_in,
                              void* d_out, int out_size, void* d_ws, size_t ws_size,
                              hipStream_t stream) {
  const float* x = (const float*)d_in[0];
  const int* src = (const int*)d_in[1];
  const int* dst = (const int*)d_in[2];
  const float* ew = (const float*)d_in[3];
  const int* mn = (const int*)d_in[4];
  const float* token = (const float*)d_in[5];

  const float* W[25];
  for (int i = 0; i < 20; ++i) W[i] = (const float*)d_in[6 + i];
  const float* W_e2d = (const float*)d_in[26];
  const float* Wnp = (const float*)d_in[27];
  const float* bnp = (const float*)d_in[28];
  const float* ln_g = (const float*)d_in[29];
  const float* ln_b = (const float*)d_in[30];

  const int Nn = in_sizes[0] / 128;   // 50000
  const int E = in_sizes[1];          // 600000
  const int nmask = in_sizes[4];      // 10000
  const int nb = (Nn + SCAN_CHUNK - 1) / SCAN_CHUNK;  // 49

  // workspace layout
  float* bufA = (float*)d_ws;                      // N*128 f32
  float* bufP = bufA + (size_t)Nn * 128;           // N*128 f32
  float* bufN = bufP + (size_t)Nn * 128;           // N*128 f32
  int* deg = (int*)(bufN + (size_t)Nn * 128);      // N int
  int* cur = deg + Nn;                             // N int
  int* off = cur + Nn;                             // N+1 int
  int* esrc = off + Nn + 1;                        // E int
  float* eww = (float*)(esrc + E);                 // E f32
  int* bsum = (int*)(eww + E);                     // nb int
  int* bbase = bsum + 64;                          // nb int
  float* WpP = (float*)(bbase + 64);               // 64*64 f32 (dec0 Wp @ W_e2d)
  float* WsP = WpP + 64 * 64;                      // 96*64 f32 (dec0 Ws @ W_e2d)

  // ---- fold encoder_to_decoder into dec0 weights (tiny) ----
  matmul_small_kernel<<<(64 * 64 + 255) / 256, 256, 0, stream>>>(W[10], W_e2d, WpP, 64, 64, 64);
  matmul_small_kernel<<<(96 * 64 + 255) / 256, 256, 0, stream>>>(W[12], W_e2d, WsP, 96, 64, 64);

  // ---- CSR build (once; graph identical across layers) ----
  hipMemsetAsync(deg, 0, (size_t)Nn * 2 * sizeof(int), stream);  // deg + cur
  hist_kernel<<<(E + 255) / 256, 256, 0, stream>>>(dst, deg, E);
  blocksum_kernel<<<nb, 256, 0, stream>>>(deg, bsum, Nn);
  bscan_kernel<<<1, 64, 0, stream>>>(bsum, bbase, off + Nn, nb);
  chunkscan_kernel<<<nb, 256, 0, stream>>>(deg, bbase, off, Nn);
  scatter_kernel<<<(E + 255) / 256, 256, 0, stream>>>(src, dst, ew, off, cur, esrc, eww, E);

  // h = x; h[mask_nodes] = token
  {
    int n4 = Nn * 128 / 4;
    copy4_kernel<<<(n4 + 255) / 256, 256, 0, stream>>>((const float4*)x, (float4*)bufA, n4);
    mask_scatter_kernel<<<(nmask * 32 + 255) / 256, 256, 0, stream>>>(mn, token, bufA, nmask);
  }

  auto run_sage = [&](const float* Wp, const float* bp, const float* Ws,
                      const float* Wn, const float* b, int din, int dout) {
    // p = relu(h @ Wp^T + bp)
    launch_gemm(bufA, Wp, din, nullptr, nullptr, 0, bp, 1, bufP, din, Nn, stream);
    // neigh = segment_max(p[src]*ew, dst); zero-degree rows -> 0
    int lanes = din >> 2;
    long long tot = (long long)Nn * lanes;
    int nblocks = (int)((tot + 255) / 256);
    neigh_csr_kernel<<<nblocks, 256, 0, stream>>>(bufP, off, esrc, eww, bufN, din, lanes, Nn);
    // out = relu(h @ Ws^T + neigh @ Wn^T + b)
    launch_gemm(bufA, Ws, din, bufN, Wn, din, b, 1, bufP, dout, Nn, stream);
    float* t = bufA; bufA = bufP; bufP = t;
  };

  // encoder
  run_sage(W[0], W[1], W[2], W[3], W[4], 128, 96);    // enc0
  run_sage(W[5], W[6], W[7], W[8], W[9], 96, 64);     // enc1

  // node_pred + layernorm -> n_scores (out section 3)
  float* out_r = (float*)d_out;
  float* out_x = out_r + (size_t)nmask * 128;
  float* out_ns = out_x + (size_t)nmask * 128;
  nodepred_ln_kernel<<<(Nn + 15) / 16, 256, 0, stream>>>(bufA, Wnp, bnp, ln_g, ln_b, out_ns, Nn);

  // decoder (e2d folded into dec0 weights: r = h2@W_e2d^T absorbed)
  run_sage(WpP, W[11], WsP, W[13], W[14], 64, 96);       // dec0 (+e2d)
  run_sage(W[15], W[16], W[17], W[18], W[19], 96, 128);  // dec1

  // outputs 1 & 2
  gather_out_kernel<<<(nmask * 32 + 255) / 256, 256, 0, stream>>>(mn, bufA, x, out_r, out_x, nmask);
}

// Round 5
// 511.027 us; speedup vs baseline: 5.4544x; 1.1047x over previous
//
#include <hip/hip_runtime.h>

#define EPS_LN 1e-5f

typedef __attribute__((ext_vector_type(4))) float f32x4;
typedef __attribute__((ext_vector_type(4))) int i32x4;

// ---------------------------------------------------------------------------
// copy x -> H (float4 grid)
__global__ __launch_bounds__(256) void copy4_kernel(const float4* __restrict__ in,
                                                    float4* __restrict__ out, int n4) {
  int i = blockIdx.x * 256 + threadIdx.x;
  if (i < n4) out[i] = in[i];
}

// scatter mask_token into H rows listed in mn
__global__ __launch_bounds__(256) void mask_scatter_kernel(const int* __restrict__ mn,
                                                           const float* __restrict__ token,
                                                           float* __restrict__ H, int nmask) {
  int gid = blockIdx.x * 256 + threadIdx.x;
  if (gid >= nmask * 32) return;
  int i = gid >> 5;
  int c4 = (gid & 31) << 2;
  int r = mn[i];
  *(float4*)(H + (size_t)r * 128 + c4) = *(const float4*)(token + c4);
}

// ---------------------------------------------------------------------------
// CSR build: histogram of dst
__global__ __launch_bounds__(256) void hist_kernel(const int* __restrict__ dst,
                                                   int* __restrict__ deg, int nE) {
  int e = blockIdx.x * 256 + threadIdx.x;
  if (e < nE) atomicAdd(deg + dst[e], 1);
}

// ---- 3-phase parallel exclusive scan of deg[n] -> off[n+1] ----
#define SCAN_CHUNK 1024

__global__ __launch_bounds__(256) void blocksum_kernel(const int* __restrict__ deg,
                                                       int* __restrict__ bsum, int n) {
  __shared__ int red[256];
  int base = blockIdx.x * SCAN_CHUNK;
  int tid = threadIdx.x;
  int s = 0;
#pragma unroll
  for (int t = 0; t < SCAN_CHUNK / 256; ++t) {
    int g = base + tid + t * 256;
    if (g < n) s += deg[g];
  }
  red[tid] = s;
  __syncthreads();
  for (int ofs = 128; ofs > 0; ofs >>= 1) {
    if (tid < ofs) red[tid] += red[tid + ofs];
    __syncthreads();
  }
  if (tid == 0) bsum[blockIdx.x] = red[0];
}

__global__ __launch_bounds__(64) void bscan_kernel(const int* __restrict__ bsum,
                                                   int* __restrict__ bbase,
                                                   int* __restrict__ off_n, int nb) {
  int tid = threadIdx.x;
  int v = (tid < nb) ? bsum[tid] : 0;
  int incl = v;
#pragma unroll
  for (int ofs = 1; ofs < 64; ofs <<= 1) {
    int u = __shfl_up(incl, ofs, 64);
    if (tid >= ofs) incl += u;
  }
  if (tid < nb) bbase[tid] = incl - v;
  if (tid == nb - 1) off_n[0] = incl;
}

__global__ __launch_bounds__(256) void chunkscan_kernel(const int* __restrict__ deg,
                                                        const int* __restrict__ bbase,
                                                        int* __restrict__ off, int n) {
  __shared__ int part[256];
  int tid = threadIdx.x;
  int base = blockIdx.x * SCAN_CHUNK;
  int g0 = base + tid * 4;
  int loc[4];
  int s = 0;
#pragma unroll
  for (int j = 0; j < 4; ++j) {
    int g = g0 + j;
    int d = (g < n) ? deg[g] : 0;
    loc[j] = s;
    s += d;
  }
  part[tid] = s;
  __syncthreads();
  for (int ofs = 1; ofs < 256; ofs <<= 1) {
    int v = 0;
    if (tid >= ofs) v = part[tid - ofs];
    __syncthreads();
    if (tid >= ofs) part[tid] += v;
    __syncthreads();
  }
  int pre = (tid == 0) ? 0 : part[tid - 1];
  int b = bbase[blockIdx.x] + pre;
#pragma unroll
  for (int j = 0; j < 4; ++j) {
    int g = g0 + j;
    if (g < n) off[g] = b + loc[j];
  }
}

// scatter edges into dst-sorted order
__global__ __launch_bounds__(256) void scatter_kernel(const int* __restrict__ src,
                                                      const int* __restrict__ dst,
                                                      const float* __restrict__ ew,
                                                      const int* __restrict__ off,
                                                      int* __restrict__ cur,
                                                      int* __restrict__ esrc,
                                                      float* __restrict__ eww, int nE) {
  int e = blockIdx.x * 256 + threadIdx.x;
  if (e >= nE) return;
  int d = dst[e];
  int pos = off[d] + atomicAdd(cur + d, 1);
  esrc[pos] = src[e];
  eww[pos] = ew[e];
}

// ---------------------------------------------------------------------------
// per-node segment max over CSR: din/4 lanes per node, one float4 per lane
__global__ __launch_bounds__(256) void neigh_csr_kernel(
    const float* __restrict__ P, const int* __restrict__ off,
    const int* __restrict__ esrc, const float* __restrict__ eww,
    float* __restrict__ neigh, int din, int lanes, int nN) {
  int gid = blockIdx.x * 256 + threadIdx.x;
  int v = gid / lanes;
  int c = (gid - v * lanes) << 2;
  if (v >= nN) return;
  int jlo = off[v], jhi = off[v + 1];
  float4 m = make_float4(0.f, 0.f, 0.f, 0.f);
  for (int j = jlo; j < jhi; ++j) {
    int s = esrc[j];
    float w = eww[j];
    float4 p = *(const float4*)(P + (size_t)s * din + c);
    m.x = fmaxf(m.x, p.x * w);
    m.y = fmaxf(m.y, p.y * w);
    m.z = fmaxf(m.z, p.z * w);
    m.w = fmaxf(m.w, p.w * w);
  }
  *(float4*)(neigh + (size_t)v * din + c) = m;
}

// ---------------------------------------------------------------------------
// small weight-combine: C[M][N] = A[M][K] @ B[K][N]  (row-major, tiny)
__global__ __launch_bounds__(256) void matmul_small_kernel(const float* __restrict__ A,
                                                           const float* __restrict__ B,
                                                           float* __restrict__ C,
                                                           int M, int K, int N) {
  int idx = blockIdx.x * 256 + threadIdx.x;
  if (idx >= M * N) return;
  int o = idx / N, i = idx - o * N;
  float s = 0.f;
  for (int k = 0; k < K; ++k) s += A[o * K + k] * B[k * N + i];
  C[idx] = s;
}

// ---------------------------------------------------------------------------
// MFMA split-bf16 GEMM: C[nrows, BN] = act( A1@W1^T (+ A2@W2^T) (+bias) )
// f32 in/out; internally A,W split into bf16 hi+lo, 3-term MFMA (hh+hl+lh).
// Block: 256 thr = 4 waves; tile 64 rows x BN; wave w owns rows w*16..w*16+15.
// v_mfma_f32_16x16x32_bf16: A[row=lane&15][k=8*(lane>>4)+e],
//                           B[k=8*(lane>>4)+e][col=lane&15],
//                           D[row=4*(lane>>4)+q][col=lane&15].
__device__ inline void mfma_b16(f32x4& acc, i32x4 a, i32x4 b) {
  asm volatile("v_mfma_f32_16x16x32_bf16 %0, %1, %2, %0"
               : "+v"(acc)
               : "v"(a), "v"(b));
}

__device__ inline void split_bf16(float x, unsigned short& hi, unsigned short& lo) {
  unsigned int bits = __float_as_uint(x);
  hi = (unsigned short)(bits >> 16);
  float hif = __uint_as_float((unsigned int)hi << 16);
  float res = x - hif;
  lo = (unsigned short)(__float_as_uint(res) >> 16);
}

template <int TNT>  // BN = TNT*16
__global__ __launch_bounds__(256) void mfma_gemm_kernel(
    const float* __restrict__ A1, const float* __restrict__ W1, int k1,
    const float* __restrict__ A2, const float* __restrict__ W2, int k2,
    const float* __restrict__ bias, int relu,
    float* __restrict__ C, int nrows) {
  constexpr int BN = TNT * 16;
  constexpr int WS = 136;  // W LDS row stride (ushort): 68 words -> 4c mod 32 spread
  constexpr int AS = 40;   // A LDS row stride (ushort): 20 words -> 20r mod 32 spread
  __shared__ unsigned short Wh[BN][WS];
  __shared__ unsigned short Wl[BN][WS];
  __shared__ unsigned short Ah[64][AS];
  __shared__ unsigned short Al[64][AS];

  const int tid = threadIdx.x;
  const int lane = tid & 63;
  const int wv = tid >> 6;      // wave 0..3 -> row band wv*16
  const int lr = lane & 15;     // frag row (A) / col (B,D)
  const int lg = lane >> 4;     // k-granule 0..3
  const int row0 = blockIdx.x * 64;

  f32x4 acc[TNT];
#pragma unroll
  for (int t = 0; t < TNT; ++t) acc[t] = (f32x4)(0.f);

  for (int pass = 0; pass < 2; ++pass) {
    const float* A = pass ? A2 : A1;
    const float* W = pass ? W2 : W1;
    const int K = pass ? k2 : k1;
    if (A == nullptr) continue;  // uniform across block

    // convert W (BN x K f32) -> bf16 hi/lo planes in LDS
    {
      int tot4 = BN * K / 4;
      for (int i = tid; i < tot4; i += 256) {
        int e0 = i * 4;
        int col = e0 / K;
        int kk = e0 - col * K;
        float4 v = *(const float4*)(W + e0);
        unsigned short h0, l0, h1, l1, h2, l2, h3, l3;
        split_bf16(v.x, h0, l0);
        split_bf16(v.y, h1, l1);
        split_bf16(v.z, h2, l2);
        split_bf16(v.w, h3, l3);
        Wh[col][kk + 0] = h0; Wh[col][kk + 1] = h1;
        Wh[col][kk + 2] = h2; Wh[col][kk + 3] = h3;
        Wl[col][kk + 0] = l0; Wl[col][kk + 1] = l1;
        Wl[col][kk + 2] = l2; Wl[col][kk + 3] = l3;
      }
    }

    for (int cb = 0; cb < K; cb += 32) {
      // stage A chunk: 64 rows x 32 k, convert to hi/lo
      {
        int r = tid >> 2;
        int k0 = (tid & 3) * 8;
        int gr = row0 + r;
        float4 v0 = make_float4(0.f, 0.f, 0.f, 0.f);
        float4 v1 = make_float4(0.f, 0.f, 0.f, 0.f);
        if (gr < nrows) {
          const float* ap = A + (size_t)gr * K + cb + k0;
          v0 = *(const float4*)ap;
          v1 = *(const float4*)(ap + 4);
        }
        float vv[8] = {v0.x, v0.y, v0.z, v0.w, v1.x, v1.y, v1.z, v1.w};
#pragma unroll
        for (int j = 0; j < 8; ++j) {
          unsigned short h, l;
          split_bf16(vv[j], h, l);
          Ah[r][k0 + j] = h;
          Al[r][k0 + j] = l;
        }
      }
      __syncthreads();

      i32x4 a_h = *(const i32x4*)&Ah[wv * 16 + lr][lg * 8];
      i32x4 a_l = *(const i32x4*)&Al[wv * 16 + lr][lg * 8];
#pragma unroll
      for (int t = 0; t < TNT; ++t) {
        i32x4 b_h = *(const i32x4*)&Wh[t * 16 + lr][cb + lg * 8];
        i32x4 b_l = *(const i32x4*)&Wl[t * 16 + lr][cb + lg * 8];
        mfma_b16(acc[t], a_h, b_h);
        mfma_b16(acc[t], a_h, b_l);
        mfma_b16(acc[t], a_l, b_h);
      }
      __syncthreads();
    }
  }

  // cover MFMA->VALU write latency (asm is opaque to the scheduler)
  asm volatile("s_nop 7\n\ts_nop 7" ::);

#pragma unroll
  for (int t = 0; t < TNT; ++t) {
    int c = t * 16 + lr;
    float bv = bias ? bias[c] : 0.f;
#pragma unroll
    for (int q = 0; q < 4; ++q) {
      int r = row0 + wv * 16 + lg * 4 + q;
      if (r < nrows) {
        float v = acc[t][q] + bv;
        if (relu) v = fmaxf(v, 0.f);
        C[(size_t)r * BN + c] = v;
      }
    }
  }
}

// ---------------------------------------------------------------------------
// z = H @ Wnp^T + bnp  (H: [n,64], Wnp: [16,64]) then LayerNorm over 16 ch
__global__ __launch_bounds__(256) void nodepred_ln_kernel(
    const float* __restrict__ H, const float* __restrict__ Wnp, const float* __restrict__ bnp,
    const float* __restrict__ g, const float* __restrict__ lb,
    float* __restrict__ out, int nrows) {
  __shared__ float hs[16][64];
  int tid = threadIdx.x;
  int row0 = blockIdx.x * 16;
  {
    int r = tid >> 4;
    int c4 = (tid & 15) << 2;
    int gr = row0 + r;
    float4 v = make_float4(0.f, 0.f, 0.f, 0.f);
    if (gr < nrows) v = *(const float4*)(H + (size_t)gr * 64 + c4);
    *(float4*)&hs[r][c4] = v;
  }
  __syncthreads();
  int r = tid >> 4, j = tid & 15;
  float z = bnp[j];
  const float* wrow = Wnp + j * 64;
#pragma unroll 8
  for (int k = 0; k < 64; ++k) z += hs[r][k] * wrow[k];
  float s = z, s2 = z * z;
#pragma unroll
  for (int m = 1; m < 16; m <<= 1) {
    s += __shfl_xor(s, m, 16);
    s2 += __shfl_xor(s2, m, 16);
  }
  float mu = s * (1.f / 16.f);
  float var = s2 * (1.f / 16.f) - mu * mu;
  float o = (z - mu) * rsqrtf(var + EPS_LN) * g[j] + lb[j];
  int gr = row0 + r;
  if (gr < nrows) out[(size_t)gr * 16 + j] = o;
}

// ---------------------------------------------------------------------------
// out1[i] = R[mn[i]], out2[i] = X[mn[i]]   (rows of 128)
__global__ __launch_bounds__(256) void gather_out_kernel(
    const int* __restrict__ mn, const float* __restrict__ R, const float* __restrict__ X,
    float* __restrict__ o1, float* __restrict__ o2, int nmask) {
  int gid = blockIdx.x * 256 + threadIdx.x;
  if (gid >= nmask * 32) return;
  int i = gid >> 5, c4 = (gid & 31) << 2;
  int r = mn[i];
  *(float4*)(o1 + (size_t)i * 128 + c4) = *(const float4*)(R + (size_t)r * 128 + c4);
  *(float4*)(o2 + (size_t)i * 128 + c4) = *(const float4*)(X + (size_t)r * 128 + c4);
}

// ---------------------------------------------------------------------------
static void launch_gemm(const float* A1, const float* W1, int k1,
                        const float* A2, const float* W2, int k2,
                        const float* bias, int relu, float* C, int m, int nrows,
                        hipStream_t s) {
  int blocks = (nrows + 63) / 64;
  switch (m) {
    case 128:
      mfma_gemm_kernel<8><<<blocks, 256, 0, s>>>(A1, W1, k1, A2, W2, k2, bias, relu, C, nrows);
      break;
    case 96:
      mfma_gemm_kernel<6><<<blocks, 256, 0, s>>>(A1, W1, k1, A2, W2, k2, bias, relu, C, nrows);
      break;
    case 64:
      mfma_gemm_kernel<4><<<blocks, 256, 0, s>>>(A1, W1, k1, A2, W2, k2, bias, relu, C, nrows);
      break;
  }
}

extern "C" void kernel_launch(void* const* d_in, const int* in_sizes, int n_in,
                              void* d_out, int out_size, void* d_ws, size_t ws_size,
                              hipStream_t stream) {
  const float* x = (const float*)d_in[0];
  const int* src = (const int*)d_in[1];
  const int* dst = (const int*)d_in[2];
  const float* ew = (const float*)d_in[3];
  const int* mn = (const int*)d_in[4];
  const float* token = (const float*)d_in[5];

  const float* W[25];
  for (int i = 0; i < 20; ++i) W[i] = (const float*)d_in[6 + i];
  const float* W_e2d = (const float*)d_in[26];
  const float* Wnp = (const float*)d_in[27];
  const float* bnp = (const float*)d_in[28];
  const float* ln_g = (const float*)d_in[29];
  const float* ln_b = (const float*)d_in[30];

  const int Nn = in_sizes[0] / 128;   // 50000
  const int E = in_sizes[1];          // 600000
  const int nmask = in_sizes[4];      // 10000
  const int nb = (Nn + SCAN_CHUNK - 1) / SCAN_CHUNK;  // 49

  // workspace layout
  float* bufA = (float*)d_ws;                      // N*128 f32
  float* bufP = bufA + (size_t)Nn * 128;           // N*128 f32
  float* bufN = bufP + (size_t)Nn * 128;           // N*128 f32
  int* deg = (int*)(bufN + (size_t)Nn * 128);      // N int
  int* cur = deg + Nn;                             // N int
  int* off = cur + Nn;                             // N+1 int
  int* esrc = off + Nn + 1;                        // E int
  float* eww = (float*)(esrc + E);                 // E f32
  int* bsum = (int*)(eww + E);                     // nb int
  int* bbase = bsum + 64;                          // nb int
  float* WpP = (float*)(bbase + 64);               // 64*64 f32 (dec0 Wp @ W_e2d)
  float* WsP = WpP + 64 * 64;                      // 96*64 f32 (dec0 Ws @ W_e2d)

  // ---- fold encoder_to_decoder into dec0 weights (tiny) ----
  matmul_small_kernel<<<(64 * 64 + 255) / 256, 256, 0, stream>>>(W[10], W_e2d, WpP, 64, 64, 64);
  matmul_small_kernel<<<(96 * 64 + 255) / 256, 256, 0, stream>>>(W[12], W_e2d, WsP, 96, 64, 64);

  // ---- CSR build (once; graph identical across layers) ----
  hipMemsetAsync(deg, 0, (size_t)Nn * 2 * sizeof(int), stream);  // deg + cur
  hist_kernel<<<(E + 255) / 256, 256, 0, stream>>>(dst, deg, E);
  blocksum_kernel<<<nb, 256, 0, stream>>>(deg, bsum, Nn);
  bscan_kernel<<<1, 64, 0, stream>>>(bsum, bbase, off + Nn, nb);
  chunkscan_kernel<<<nb, 256, 0, stream>>>(deg, bbase, off, Nn);
  scatter_kernel<<<(E + 255) / 256, 256, 0, stream>>>(src, dst, ew, off, cur, esrc, eww, E);

  // h = x; h[mask_nodes] = token
  {
    int n4 = Nn * 128 / 4;
    copy4_kernel<<<(n4 + 255) / 256, 256, 0, stream>>>((const float4*)x, (float4*)bufA, n4);
    mask_scatter_kernel<<<(nmask * 32 + 255) / 256, 256, 0, stream>>>(mn, token, bufA, nmask);
  }

  auto run_sage = [&](const float* Wp, const float* bp, const float* Ws,
                      const float* Wn, const float* b, int din, int dout) {
    // p = relu(h @ Wp^T + bp)
    launch_gemm(bufA, Wp, din, nullptr, nullptr, 0, bp, 1, bufP, din, Nn, stream);
    // neigh = segment_max(p[src]*ew, dst); zero-degree rows -> 0
    int lanes = din >> 2;
    long long tot = (long long)Nn * lanes;
    int nblocks = (int)((tot + 255) / 256);
    neigh_csr_kernel<<<nblocks, 256, 0, stream>>>(bufP, off, esrc, eww, bufN, din, lanes, Nn);
    // out = relu(h @ Ws^T + neigh @ Wn^T + b)
    launch_gemm(bufA, Ws, din, bufN, Wn, din, b, 1, bufP, dout, Nn, stream);
    float* t = bufA; bufA = bufP; bufP = t;
  };

  // encoder
  run_sage(W[0], W[1], W[2], W[3], W[4], 128, 96);    // enc0
  run_sage(W[5], W[6], W[7], W[8], W[9], 96, 64);     // enc1

  // node_pred + layernorm -> n_scores (out section 3)
  float* out_r = (float*)d_out;
  float* out_x = out_r + (size_t)nmask * 128;
  float* out_ns = out_x + (size_t)nmask * 128;
  nodepred_ln_kernel<<<(Nn + 15) / 16, 256, 0, stream>>>(bufA, Wnp, bnp, ln_g, ln_b, out_ns, Nn);

  // decoder (e2d folded into dec0 weights: r = h2@W_e2d^T absorbed)
  run_sage(WpP, W[11], WsP, W[13], W[14], 64, 96);       // dec0 (+e2d)
  run_sage(W[15], W[16], W[17], W[18], W[19], 96, 128);  // dec1

  // outputs 1 & 2
  gather_out_kernel<<<(nmask * 32 + 255) / 256, 256, 0, stream>>>(mn, bufA, x, out_r, out_x, nmask);
}

// Round 7
// 508.034 us; speedup vs baseline: 5.4865x; 1.0059x over previous
//
#include <hip/hip_runtime.h>

#define EPS_LN 1e-5f

typedef __attribute__((ext_vector_type(4))) float f32x4;
typedef __attribute__((ext_vector_type(4))) int i32x4;

// ---------------------------------------------------------------------------
// copy x -> H (float4 grid)
__global__ __launch_bounds__(256) void copy4_kernel(const float4* __restrict__ in,
                                                    float4* __restrict__ out, int n4) {
  int i = blockIdx.x * 256 + threadIdx.x;
  if (i < n4) out[i] = in[i];
}

// scatter mask_token into H rows listed in mn
__global__ __launch_bounds__(256) void mask_scatter_kernel(const int* __restrict__ mn,
                                                           const float* __restrict__ token,
                                                           float* __restrict__ H, int nmask) {
  int gid = blockIdx.x * 256 + threadIdx.x;
  if (gid >= nmask * 32) return;
  int i = gid >> 5;
  int c4 = (gid & 31) << 2;
  int r = mn[i];
  *(float4*)(H + (size_t)r * 128 + c4) = *(const float4*)(token + c4);
}

// ---------------------------------------------------------------------------
// CSR build: histogram of dst
__global__ __launch_bounds__(256) void hist_kernel(const int* __restrict__ dst,
                                                   int* __restrict__ deg, int nE) {
  int e = blockIdx.x * 256 + threadIdx.x;
  if (e < nE) atomicAdd(deg + dst[e], 1);
}

// ---- 3-phase parallel exclusive scan of deg[n] -> off[n+1] ----
#define SCAN_CHUNK 1024

__global__ __launch_bounds__(256) void blocksum_kernel(const int* __restrict__ deg,
                                                       int* __restrict__ bsum, int n) {
  __shared__ int red[256];
  int base = blockIdx.x * SCAN_CHUNK;
  int tid = threadIdx.x;
  int s = 0;
#pragma unroll
  for (int t = 0; t < SCAN_CHUNK / 256; ++t) {
    int g = base + tid + t * 256;
    if (g < n) s += deg[g];
  }
  red[tid] = s;
  __syncthreads();
  for (int ofs = 128; ofs > 0; ofs >>= 1) {
    if (tid < ofs) red[tid] += red[tid + ofs];
    __syncthreads();
  }
  if (tid == 0) bsum[blockIdx.x] = red[0];
}

__global__ __launch_bounds__(64) void bscan_kernel(const int* __restrict__ bsum,
                                                   int* __restrict__ bbase,
                                                   int* __restrict__ off_n, int nb) {
  int tid = threadIdx.x;
  int v = (tid < nb) ? bsum[tid] : 0;
  int incl = v;
#pragma unroll
  for (int ofs = 1; ofs < 64; ofs <<= 1) {
    int u = __shfl_up(incl, ofs, 64);
    if (tid >= ofs) incl += u;
  }
  if (tid < nb) bbase[tid] = incl - v;
  if (tid == nb - 1) off_n[0] = incl;
}

__global__ __launch_bounds__(256) void chunkscan_kernel(const int* __restrict__ deg,
                                                        const int* __restrict__ bbase,
                                                        int* __restrict__ off, int n) {
  __shared__ int part[256];
  int tid = threadIdx.x;
  int base = blockIdx.x * SCAN_CHUNK;
  int g0 = base + tid * 4;
  int loc[4];
  int s = 0;
#pragma unroll
  for (int j = 0; j < 4; ++j) {
    int g = g0 + j;
    int d = (g < n) ? deg[g] : 0;
    loc[j] = s;
    s += d;
  }
  part[tid] = s;
  __syncthreads();
  for (int ofs = 1; ofs < 256; ofs <<= 1) {
    int v = 0;
    if (tid >= ofs) v = part[tid - ofs];
    __syncthreads();
    if (tid >= ofs) part[tid] += v;
    __syncthreads();
  }
  int pre = (tid == 0) ? 0 : part[tid - 1];
  int b = bbase[blockIdx.x] + pre;
#pragma unroll
  for (int j = 0; j < 4; ++j) {
    int g = g0 + j;
    if (g < n) off[g] = b + loc[j];
  }
}

// scatter edges into dst-sorted order; (src, ew-bits) packed -> one line/edge
__global__ __launch_bounds__(256) void scatter_kernel(const int* __restrict__ src,
                                                      const int* __restrict__ dst,
                                                      const float* __restrict__ ew,
                                                      const int* __restrict__ off,
                                                      int* __restrict__ cur,
                                                      int2* __restrict__ esw, int nE) {
  int e = blockIdx.x * 256 + threadIdx.x;
  if (e >= nE) return;
  int d = dst[e];
  int pos = off[d] + atomicAdd(cur + d, 1);
  esw[pos] = make_int2(src[e], __float_as_int(ew[e]));
}

// ---------------------------------------------------------------------------
// per-node segment max over CSR: din/4 lanes per node, one float4 per lane
__global__ __launch_bounds__(256) void neigh_csr_kernel(
    const float* __restrict__ P, const int* __restrict__ off,
    const int2* __restrict__ esw,
    float* __restrict__ neigh, int din, int lanes, int nN) {
  int gid = blockIdx.x * 256 + threadIdx.x;
  int v = gid / lanes;
  int c = (gid - v * lanes) << 2;
  if (v >= nN) return;
  int jlo = off[v], jhi = off[v + 1];
  float4 m = make_float4(0.f, 0.f, 0.f, 0.f);
  for (int j = jlo; j < jhi; ++j) {
    int2 e = esw[j];
    float w = __int_as_float(e.y);
    float4 p = *(const float4*)(P + (size_t)e.x * din + c);
    m.x = fmaxf(m.x, p.x * w);
    m.y = fmaxf(m.y, p.y * w);
    m.z = fmaxf(m.z, p.z * w);
    m.w = fmaxf(m.w, p.w * w);
  }
  *(float4*)(neigh + (size_t)v * din + c) = m;
}

// ---------------------------------------------------------------------------
// small weight-combine: C[M][N] = A[M][K] @ B[K][N]  (row-major, tiny)
__global__ __launch_bounds__(256) void matmul_small_kernel(const float* __restrict__ A,
                                                           const float* __restrict__ B,
                                                           float* __restrict__ C,
                                                           int M, int K, int N) {
  int idx = blockIdx.x * 256 + threadIdx.x;
  if (idx >= M * N) return;
  int o = idx / N, i = idx - o * N;
  float s = 0.f;
  for (int k = 0; k < K; ++k) s += A[o * K + k] * B[k * N + i];
  C[idx] = s;
}

// ---------------------------------------------------------------------------
// MFMA split-bf16 GEMM: C[nrows, BN] = act( A1@W1^T (+ A2@W2^T) (+bias) )
// f32 in/out; internally A,W split into bf16 hi+lo, 3-term MFMA (hh+hl+lh).
// Block: 256 thr = 4 waves; tile 64 rows x BN; wave w owns rows w*16..w*16+15.
// v_mfma_f32_16x16x32_bf16: A[row=lane&15][k=8*(lane>>4)+e],
//                           B[k=8*(lane>>4)+e][col=lane&15],
//                           D[row=4*(lane>>4)+q][col=lane&15].
__device__ inline void mfma_b16(f32x4& acc, i32x4 a, i32x4 b) {
  asm volatile("v_mfma_f32_16x16x32_bf16 %0, %1, %2, %0"
               : "+v"(acc)
               : "v"(a), "v"(b));
}

__device__ inline void split_bf16(float x, unsigned short& hi, unsigned short& lo) {
  unsigned int bits = __float_as_uint(x);
  hi = (unsigned short)(bits >> 16);
  float hif = __uint_as_float((unsigned int)hi << 16);
  float res = x - hif;
  lo = (unsigned short)(__float_as_uint(res) >> 16);
}

template <int TNT>  // BN = TNT*16
__global__ __launch_bounds__(256) void mfma_gemm_kernel(
    const float* __restrict__ A1, const float* __restrict__ W1, int k1,
    const float* __restrict__ A2, const float* __restrict__ W2, int k2,
    const float* __restrict__ bias, int relu,
    float* __restrict__ C, int nrows) {
  constexpr int BN = TNT * 16;
  constexpr int WS = 136;  // W LDS row stride (ushort): 68 words -> 4c mod 32 spread
  constexpr int AS = 40;   // A LDS row stride (ushort): 20 words -> 20r mod 32 spread
  __shared__ unsigned short Wh[BN][WS];
  __shared__ unsigned short Wl[BN][WS];
  __shared__ unsigned short Ah[64][AS];
  __shared__ unsigned short Al[64][AS];

  const int tid = threadIdx.x;
  const int lane = tid & 63;
  const int wv = tid >> 6;      // wave 0..3 -> row band wv*16
  const int lr = lane & 15;     // frag row (A) / col (B,D)
  const int lg = lane >> 4;     // k-granule 0..3
  const int row0 = blockIdx.x * 64;

  f32x4 acc[TNT];
#pragma unroll
  for (int t = 0; t < TNT; ++t) acc[t] = (f32x4)(0.f);

  for (int pass = 0; pass < 2; ++pass) {
    const float* A = pass ? A2 : A1;
    const float* W = pass ? W2 : W1;
    const int K = pass ? k2 : k1;
    if (A == nullptr) continue;  // uniform across block

    // convert W (BN x K f32) -> bf16 hi/lo planes in LDS
    {
      int tot4 = BN * K / 4;
      for (int i = tid; i < tot4; i += 256) {
        int e0 = i * 4;
        int col = e0 / K;
        int kk = e0 - col * K;
        float4 v = *(const float4*)(W + e0);
        unsigned short h0, l0, h1, l1, h2, l2, h3, l3;
        split_bf16(v.x, h0, l0);
        split_bf16(v.y, h1, l1);
        split_bf16(v.z, h2, l2);
        split_bf16(v.w, h3, l3);
        Wh[col][kk + 0] = h0; Wh[col][kk + 1] = h1;
        Wh[col][kk + 2] = h2; Wh[col][kk + 3] = h3;
        Wl[col][kk + 0] = l0; Wl[col][kk + 1] = l1;
        Wl[col][kk + 2] = l2; Wl[col][kk + 3] = l3;
      }
    }

    for (int cb = 0; cb < K; cb += 32) {
      // stage A chunk: 64 rows x 32 k, convert to hi/lo
      {
        int r = tid >> 2;
        int k0 = (tid & 3) * 8;
        int gr = row0 + r;
        float4 v0 = make_float4(0.f, 0.f, 0.f, 0.f);
        float4 v1 = make_float4(0.f, 0.f, 0.f, 0.f);
        if (gr < nrows) {
          const float* ap = A + (size_t)gr * K + cb + k0;
          v0 = *(const float4*)ap;
          v1 = *(const float4*)(ap + 4);
        }
        float vv[8] = {v0.x, v0.y, v0.z, v0.w, v1.x, v1.y, v1.z, v1.w};
#pragma unroll
        for (int j = 0; j < 8; ++j) {
          unsigned short h, l;
          split_bf16(vv[j], h, l);
          Ah[r][k0 + j] = h;
          Al[r][k0 + j] = l;
        }
      }
      __syncthreads();

      i32x4 a_h = *(const i32x4*)&Ah[wv * 16 + lr][lg * 8];
      i32x4 a_l = *(const i32x4*)&Al[wv * 16 + lr][lg * 8];
#pragma unroll
      for (int t = 0; t < TNT; ++t) {
        i32x4 b_h = *(const i32x4*)&Wh[t * 16 + lr][cb + lg * 8];
        i32x4 b_l = *(const i32x4*)&Wl[t * 16 + lr][cb + lg * 8];
        mfma_b16(acc[t], a_h, b_h);
        mfma_b16(acc[t], a_h, b_l);
        mfma_b16(acc[t], a_l, b_h);
      }
      __syncthreads();
    }
  }

  // cover MFMA->VALU write latency (asm is opaque to the scheduler)
  asm volatile("s_nop 7\n\ts_nop 7" ::);

#pragma unroll
  for (int t = 0; t < TNT; ++t) {
    int c = t * 16 + lr;
    float bv = bias ? bias[c] : 0.f;
#pragma unroll
    for (int q = 0; q < 4; ++q) {
      int r = row0 + wv * 16 + lg * 4 + q;
      if (r < nrows) {
        float v = acc[t][q] + bv;
        if (relu) v = fmaxf(v, 0.f);
        C[(size_t)r * BN + c] = v;
      }
    }
  }
}

// ---------------------------------------------------------------------------
// z = H @ Wnp^T + bnp  (H: [n,64], Wnp: [16,64]) then LayerNorm over 16 ch
__global__ __launch_bounds__(256) void nodepred_ln_kernel(
    const float* __restrict__ H, const float* __restrict__ Wnp, const float* __restrict__ bnp,
    const float* __restrict__ g, const float* __restrict__ lb,
    float* __restrict__ out, int nrows) {
  __shared__ float hs[16][64];
  int tid = threadIdx.x;
  int row0 = blockIdx.x * 16;
  {
    int r = tid >> 4;
    int c4 = (tid & 15) << 2;
    int gr = row0 + r;
    float4 v = make_float4(0.f, 0.f, 0.f, 0.f);
    if (gr < nrows) v = *(const float4*)(H + (size_t)gr * 64 + c4);
    *(float4*)&hs[r][c4] = v;
  }
  __syncthreads();
  int r = tid >> 4, j = tid & 15;
  float z = bnp[j];
  const float* wrow = Wnp + j * 64;
#pragma unroll 8
  for (int k = 0; k < 64; ++k) z += hs[r][k] * wrow[k];
  float s = z, s2 = z * z;
#pragma unroll
  for (int m = 1; m < 16; m <<= 1) {
    s += __shfl_xor(s, m, 16);
    s2 += __shfl_xor(s2, m, 16);
  }
  float mu = s * (1.f / 16.f);
  float var = s2 * (1.f / 16.f) - mu * mu;
  float o = (z - mu) * rsqrtf(var + EPS_LN) * g[j] + lb[j];
  int gr = row0 + r;
  if (gr < nrows) out[(size_t)gr * 16 + j] = o;
}

// ---------------------------------------------------------------------------
// out1[i] = R[mn[i]], out2[i] = X[mn[i]]   (rows of 128)
__global__ __launch_bounds__(256) void gather_out_kernel(
    const int* __restrict__ mn, const float* __restrict__ R, const float* __restrict__ X,
    float* __restrict__ o1, float* __restrict__ o2, int nmask) {
  int gid = blockIdx.x * 256 + threadIdx.x;
  if (gid >= nmask * 32) return;
  int i = gid >> 5, c4 = (gid & 31) << 2;
  int r = mn[i];
  *(float4*)(o1 + (size_t)i * 128 + c4) = *(const float4*)(R + (size_t)r * 128 + c4);
  *(float4*)(o2 + (size_t)i * 128 + c4) = *(const float4*)(X + (size_t)r * 128 + c4);
}

// ---------------------------------------------------------------------------
static void launch_gemm(const float* A1, const float* W1, int k1,
                        const float* A2, const float* W2, int k2,
                        const float* bias, int relu, float* C, int m, int nrows,
                        hipStream_t s) {
  int blocks = (nrows + 63) / 64;
  switch (m) {
    case 128:
      mfma_gemm_kernel<8><<<blocks, 256, 0, s>>>(A1, W1, k1, A2, W2, k2, bias, relu, C, nrows);
      break;
    case 96:
      mfma_gemm_kernel<6><<<blocks, 256, 0, s>>>(A1, W1, k1, A2, W2, k2, bias, relu, C, nrows);
      break;
    case 64:
      mfma_gemm_kernel<4><<<blocks, 256, 0, s>>>(A1, W1, k1, A2, W2, k2, bias, relu, C, nrows);
      break;
  }
}

extern "C" void kernel_launch(void* const* d_in, const int* in_sizes, int n_in,
                              void* d_out, int out_size, void* d_ws, size_t ws_size,
                              hipStream_t stream) {
  const float* x = (const float*)d_in[0];
  const int* src = (const int*)d_in[1];
  const int* dst = (const int*)d_in[2];
  const float* ew = (const float*)d_in[3];
  const int* mn = (const int*)d_in[4];
  const float* token = (const float*)d_in[5];

  const float* W[20];
  for (int i = 0; i < 20; ++i) W[i] = (const float*)d_in[6 + i];
  const float* W_e2d = (const float*)d_in[26];
  const float* Wnp = (const float*)d_in[27];
  const float* bnp = (const float*)d_in[28];
  const float* ln_g = (const float*)d_in[29];
  const float* ln_b = (const float*)d_in[30];

  const int Nn = in_sizes[0] / 128;   // 50000
  const int E = in_sizes[1];          // 600000
  const int nmask = in_sizes[4];      // 10000
  const int nb = (Nn + SCAN_CHUNK - 1) / SCAN_CHUNK;  // 49

  // workspace layout
  float* bufA = (float*)d_ws;                      // N*128 f32
  float* bufP = bufA + (size_t)Nn * 128;           // N*128 f32
  float* bufN = bufP + (size_t)Nn * 128;           // N*128 f32
  int* deg = (int*)(bufN + (size_t)Nn * 128);      // N int
  int* cur = deg + Nn;                             // N int
  int2* esw = (int2*)(cur + Nn);                   // E int2 (8B aligned)
  int* off = (int*)(esw + E);                      // N+1 int
  int* bsum = off + Nn + 1;                        // 64 int
  int* bbase = bsum + 64;                          // 64 int
  float* WpP = (float*)(bbase + 64);               // 64*64 f32 (dec0 Wp @ W_e2d)
  float* WsP = WpP + 64 * 64;                      // 96*64 f32 (dec0 Ws @ W_e2d)

  // ---- fold encoder_to_decoder into dec0 weights (tiny) ----
  matmul_small_kernel<<<(64 * 64 + 255) / 256, 256, 0, stream>>>(W[10], W_e2d, WpP, 64, 64, 64);
  matmul_small_kernel<<<(96 * 64 + 255) / 256, 256, 0, stream>>>(W[12], W_e2d, WsP, 96, 64, 64);

  // ---- CSR build (once; graph identical across layers) ----
  hipMemsetAsync(deg, 0, (size_t)Nn * 2 * sizeof(int), stream);  // deg + cur
  hist_kernel<<<(E + 255) / 256, 256, 0, stream>>>(dst, deg, E);
  blocksum_kernel<<<nb, 256, 0, stream>>>(deg, bsum, Nn);
  bscan_kernel<<<1, 64, 0, stream>>>(bsum, bbase, off + Nn, nb);
  chunkscan_kernel<<<nb, 256, 0, stream>>>(deg, bbase, off, Nn);
  scatter_kernel<<<(E + 255) / 256, 256, 0, stream>>>(src, dst, ew, off, cur, esw, E);

  // h = x; h[mask_nodes] = token
  {
    int n4 = Nn * 128 / 4;
    copy4_kernel<<<(n4 + 255) / 256, 256, 0, stream>>>((const float4*)x, (float4*)bufA, n4);
    mask_scatter_kernel<<<(nmask * 32 + 255) / 256, 256, 0, stream>>>(mn, token, bufA, nmask);
  }

  auto run_sage = [&](const float* Wp, const float* bp, const float* Ws,
                      const float* Wn, const float* b, int din, int dout) {
    // p = relu(h @ Wp^T + bp)
    launch_gemm(bufA, Wp, din, nullptr, nullptr, 0, bp, 1, bufP, din, Nn, stream);
    // neigh = segment_max(p[src]*ew, dst); zero-degree rows -> 0
    int lanes = din >> 2;
    long long tot = (long long)Nn * lanes;
    int nblocks = (int)((tot + 255) / 256);
    neigh_csr_kernel<<<nblocks, 256, 0, stream>>>(bufP, off, esw, bufN, din, lanes, Nn);
    // out = relu(h @ Ws^T + neigh @ Wn^T + b)
    launch_gemm(bufA, Ws, din, bufN, Wn, din, b, 1, bufP, dout, Nn, stream);
    float* t = bufA; bufA = bufP; bufP = t;
  };

  // encoder
  run_sage(W[0], W[1], W[2], W[3], W[4], 128, 96);    // enc0
  run_sage(W[5], W[6], W[7], W[8], W[9], 96, 64);     // enc1

  // node_pred + layernorm -> n_scores (out section 3)
  float* out_r = (float*)d_out;
  float* out_x = out_r + (size_t)nmask * 128;
  float* out_ns = out_x + (size_t)nmask * 128;
  nodepred_ln_kernel<<<(Nn + 15) / 16, 256, 0, stream>>>(bufA, Wnp, bnp, ln_g, ln_b, out_ns, Nn);

  // decoder (e2d folded into dec0 weights: r = h2@W_e2d^T absorbed)
  run_sage(WpP, W[11], WsP, W[13], W[14], 64, 96);       // dec0 (+e2d)
  run_sage(W[15], W[16], W[17], W[18], W[19], 96, 128);  // dec1

  // outputs 1 & 2
  gather_out_kernel<<<(nmask * 32 + 255) / 256, 256, 0, stream>>>(mn, bufA, x, out_r, out_x, nmask);
}

// Round 8
// 455.388 us; speedup vs baseline: 6.1208x; 1.1156x over previous
//
#include <hip/hip_runtime.h>

#define EPS_LN 1e-5f

typedef __attribute__((ext_vector_type(4))) float f32x4;
typedef __attribute__((ext_vector_type(4))) int i32x4;

// ---------------------------------------------------------------------------
// copy x -> H (float4 grid)
__global__ __launch_bounds__(256) void copy4_kernel(const float4* __restrict__ in,
                                                    float4* __restrict__ out, int n4) {
  int i = blockIdx.x * 256 + threadIdx.x;
  if (i < n4) out[i] = in[i];
}

// scatter mask_token into H rows listed in mn
__global__ __launch_bounds__(256) void mask_scatter_kernel(const int* __restrict__ mn,
                                                           const float* __restrict__ token,
                                                           float* __restrict__ H, int nmask) {
  int gid = blockIdx.x * 256 + threadIdx.x;
  if (gid >= nmask * 32) return;
  int i = gid >> 5;
  int c4 = (gid & 31) << 2;
  int r = mn[i];
  *(float4*)(H + (size_t)r * 128 + c4) = *(const float4*)(token + c4);
}

// ---------------------------------------------------------------------------
// CSR build: histogram of dst
__global__ __launch_bounds__(256) void hist_kernel(const int* __restrict__ dst,
                                                   int* __restrict__ deg, int nE) {
  int e = blockIdx.x * 256 + threadIdx.x;
  if (e < nE) atomicAdd(deg + dst[e], 1);
}

// ---- 3-phase parallel exclusive scan of deg[n] -> off[n+1] ----
#define SCAN_CHUNK 1024

__global__ __launch_bounds__(256) void blocksum_kernel(const int* __restrict__ deg,
                                                       int* __restrict__ bsum, int n) {
  __shared__ int red[256];
  int base = blockIdx.x * SCAN_CHUNK;
  int tid = threadIdx.x;
  int s = 0;
#pragma unroll
  for (int t = 0; t < SCAN_CHUNK / 256; ++t) {
    int g = base + tid + t * 256;
    if (g < n) s += deg[g];
  }
  red[tid] = s;
  __syncthreads();
  for (int ofs = 128; ofs > 0; ofs >>= 1) {
    if (tid < ofs) red[tid] += red[tid + ofs];
    __syncthreads();
  }
  if (tid == 0) bsum[blockIdx.x] = red[0];
}

__global__ __launch_bounds__(64) void bscan_kernel(const int* __restrict__ bsum,
                                                   int* __restrict__ bbase,
                                                   int* __restrict__ off_n, int nb) {
  int tid = threadIdx.x;
  int v = (tid < nb) ? bsum[tid] : 0;
  int incl = v;
#pragma unroll
  for (int ofs = 1; ofs < 64; ofs <<= 1) {
    int u = __shfl_up(incl, ofs, 64);
    if (tid >= ofs) incl += u;
  }
  if (tid < nb) bbase[tid] = incl - v;
  if (tid == nb - 1) off_n[0] = incl;
}

__global__ __launch_bounds__(256) void chunkscan_kernel(const int* __restrict__ deg,
                                                        const int* __restrict__ bbase,
                                                        int* __restrict__ off, int n) {
  __shared__ int part[256];
  int tid = threadIdx.x;
  int base = blockIdx.x * SCAN_CHUNK;
  int g0 = base + tid * 4;
  int loc[4];
  int s = 0;
#pragma unroll
  for (int j = 0; j < 4; ++j) {
    int g = g0 + j;
    int d = (g < n) ? deg[g] : 0;
    loc[j] = s;
    s += d;
  }
  part[tid] = s;
  __syncthreads();
  for (int ofs = 1; ofs < 256; ofs <<= 1) {
    int v = 0;
    if (tid >= ofs) v = part[tid - ofs];
    __syncthreads();
    if (tid >= ofs) part[tid] += v;
    __syncthreads();
  }
  int pre = (tid == 0) ? 0 : part[tid - 1];
  int b = bbase[blockIdx.x] + pre;
#pragma unroll
  for (int j = 0; j < 4; ++j) {
    int g = g0 + j;
    if (g < n) off[g] = b + loc[j];
  }
}

// scatter edges into dst-sorted order; (src, ew-bits) packed -> one line/edge
__global__ __launch_bounds__(256) void scatter_kernel(const int* __restrict__ src,
                                                      const int* __restrict__ dst,
                                                      const float* __restrict__ ew,
                                                      const int* __restrict__ off,
                                                      int* __restrict__ cur,
                                                      int2* __restrict__ esw, int nE) {
  int e = blockIdx.x * 256 + threadIdx.x;
  if (e >= nE) return;
  int d = dst[e];
  int pos = off[d] + atomicAdd(cur + d, 1);
  esw[pos] = make_int2(src[e], __float_as_int(ew[e]));
}

// ---------------------------------------------------------------------------
// per-node segment max over CSR: din/4 lanes per node, one float4 per lane.
// 2x unrolled with independent accumulators -> 2x memory-level parallelism.
__global__ __launch_bounds__(256) void neigh_csr_kernel(
    const float* __restrict__ P, const int* __restrict__ off,
    const int2* __restrict__ esw,
    float* __restrict__ neigh, int din, int lanes, int nN) {
  int gid = blockIdx.x * 256 + threadIdx.x;
  int v = gid / lanes;
  int c = (gid - v * lanes) << 2;
  if (v >= nN) return;
  int jlo = off[v], jhi = off[v + 1];
  float4 m0 = make_float4(0.f, 0.f, 0.f, 0.f);
  float4 m1 = m0;
  int j = jlo;
  for (; j + 2 <= jhi; j += 2) {
    int2 e0 = esw[j];
    int2 e1 = esw[j + 1];
    float4 p0 = *(const float4*)(P + (size_t)e0.x * din + c);
    float4 p1 = *(const float4*)(P + (size_t)e1.x * din + c);
    float w0 = __int_as_float(e0.y);
    float w1 = __int_as_float(e1.y);
    m0.x = fmaxf(m0.x, p0.x * w0);
    m0.y = fmaxf(m0.y, p0.y * w0);
    m0.z = fmaxf(m0.z, p0.z * w0);
    m0.w = fmaxf(m0.w, p0.w * w0);
    m1.x = fmaxf(m1.x, p1.x * w1);
    m1.y = fmaxf(m1.y, p1.y * w1);
    m1.z = fmaxf(m1.z, p1.z * w1);
    m1.w = fmaxf(m1.w, p1.w * w1);
  }
  if (j < jhi) {
    int2 e = esw[j];
    float w = __int_as_float(e.y);
    float4 p = *(const float4*)(P + (size_t)e.x * din + c);
    m0.x = fmaxf(m0.x, p.x * w);
    m0.y = fmaxf(m0.y, p.y * w);
    m0.z = fmaxf(m0.z, p.z * w);
    m0.w = fmaxf(m0.w, p.w * w);
  }
  m0.x = fmaxf(m0.x, m1.x);
  m0.y = fmaxf(m0.y, m1.y);
  m0.z = fmaxf(m0.z, m1.z);
  m0.w = fmaxf(m0.w, m1.w);
  *(float4*)(neigh + (size_t)v * din + c) = m0;
}

// ---------------------------------------------------------------------------
// small weight-combine: C[M][N] = A[M][K] @ B[K][N]  (row-major, tiny)
__global__ __launch_bounds__(256) void matmul_small_kernel(const float* __restrict__ A,
                                                           const float* __restrict__ B,
                                                           float* __restrict__ C,
                                                           int M, int K, int N) {
  int idx = blockIdx.x * 256 + threadIdx.x;
  if (idx >= M * N) return;
  int o = idx / N, i = idx - o * N;
  float s = 0.f;
  for (int k = 0; k < K; ++k) s += A[o * K + k] * B[k * N + i];
  C[idx] = s;
}

// ---------------------------------------------------------------------------
// split helpers
__device__ inline void mfma_b16(f32x4& acc, i32x4 a, i32x4 b) {
  asm volatile("v_mfma_f32_16x16x32_bf16 %0, %1, %2, %0"
               : "+v"(acc)
               : "v"(a), "v"(b));
}

__device__ inline void split_bf16(float x, unsigned short& hi, unsigned short& lo) {
  unsigned int bits = __float_as_uint(x);
  hi = (unsigned short)(bits >> 16);
  float hif = __uint_as_float((unsigned int)hi << 16);
  float res = x - hif;
  lo = (unsigned short)(__float_as_uint(res) >> 16);
}

// one-shot split of all weight matrices into bf16 hi/lo planes
struct SplitWArgs {
  const float* src[12];
  unsigned short* dh[12];
  unsigned short* dl[12];
  int n[12];
};

__global__ __launch_bounds__(256) void split_w_kernel(SplitWArgs a) {
  int m = blockIdx.y;
  int i = (blockIdx.x * 256 + threadIdx.x) * 4;
  if (i >= a.n[m]) return;
  float4 v = *(const float4*)(a.src[m] + i);
  unsigned short h[4], l[4];
  split_bf16(v.x, h[0], l[0]);
  split_bf16(v.y, h[1], l[1]);
  split_bf16(v.z, h[2], l[2]);
  split_bf16(v.w, h[3], l[3]);
  *(uint2*)(a.dh[m] + i) = make_uint2((unsigned)h[0] | ((unsigned)h[1] << 16),
                                      (unsigned)h[2] | ((unsigned)h[3] << 16));
  *(uint2*)(a.dl[m] + i) = make_uint2((unsigned)l[0] | ((unsigned)l[1] << 16),
                                      (unsigned)l[2] | ((unsigned)l[3] << 16));
}

// ---------------------------------------------------------------------------
// MFMA split-bf16 GEMM: C[nrows, BN] = act( A1@W1^T (+ A2@W2^T) (+bias) )
// A f32 (split on the fly); W pre-split global hi/lo planes (LDS copy only).
// Block: 256 thr = 4 waves; tile 64 rows x BN; wave w owns rows w*16..w*16+15.
// v_mfma_f32_16x16x32_bf16: A[row=lane&15][k=8*(lane>>4)+e],
//                           B[k=8*(lane>>4)+e][col=lane&15],
//                           D[row=4*(lane>>4)+q][col=lane&15].
template <int TNT>  // BN = TNT*16
__global__ __launch_bounds__(256) void mfma_gemm_kernel(
    const float* __restrict__ A1, const unsigned short* __restrict__ Wh1,
    const unsigned short* __restrict__ Wl1, int k1,
    const float* __restrict__ A2, const unsigned short* __restrict__ Wh2,
    const unsigned short* __restrict__ Wl2, int k2,
    const float* __restrict__ bias, int relu,
    float* __restrict__ C, int nrows) {
  constexpr int BN = TNT * 16;
  constexpr int WS = 136;  // W LDS row stride (ushort)
  constexpr int AS = 40;   // A LDS row stride (ushort)
  __shared__ __align__(16) unsigned short Wh[BN][WS];
  __shared__ __align__(16) unsigned short Wl[BN][WS];
  __shared__ __align__(16) unsigned short Ah[64][AS];
  __shared__ __align__(16) unsigned short Al[64][AS];

  const int tid = threadIdx.x;
  const int lane = tid & 63;
  const int wv = tid >> 6;      // wave 0..3 -> row band wv*16
  const int lr = lane & 15;     // frag row (A) / col (B,D)
  const int lg = lane >> 4;     // k-granule 0..3
  const int row0 = blockIdx.x * 64;

  f32x4 acc[TNT];
#pragma unroll
  for (int t = 0; t < TNT; ++t) acc[t] = (f32x4)(0.f);

  for (int pass = 0; pass < 2; ++pass) {
    const float* A = pass ? A2 : A1;
    const unsigned short* Whp = pass ? Wh2 : Wh1;
    const unsigned short* Wlp = pass ? Wl2 : Wl1;
    const int K = pass ? k2 : k1;
    if (A == nullptr) continue;  // uniform across block

    // copy pre-split W planes (BN x K ushort each) into LDS, 16B chunks
    {
      int tot8 = BN * K / 8;
      for (int i = tid; i < tot8; i += 256) {
        int e0 = i * 8;
        int col = e0 / K;
        int kk = e0 - col * K;
        *(uint4*)&Wh[col][kk] = *(const uint4*)(Whp + e0);
        *(uint4*)&Wl[col][kk] = *(const uint4*)(Wlp + e0);
      }
    }

    for (int cb = 0; cb < K; cb += 32) {
      // stage A chunk: 64 rows x 32 k, convert to hi/lo
      {
        int r = tid >> 2;
        int k0 = (tid & 3) * 8;
        int gr = row0 + r;
        float4 v0 = make_float4(0.f, 0.f, 0.f, 0.f);
        float4 v1 = make_float4(0.f, 0.f, 0.f, 0.f);
        if (gr < nrows) {
          const float* ap = A + (size_t)gr * K + cb + k0;
          v0 = *(const float4*)ap;
          v1 = *(const float4*)(ap + 4);
        }
        float vv[8] = {v0.x, v0.y, v0.z, v0.w, v1.x, v1.y, v1.z, v1.w};
#pragma unroll
        for (int j = 0; j < 8; ++j) {
          unsigned short h, l;
          split_bf16(vv[j], h, l);
          Ah[r][k0 + j] = h;
          Al[r][k0 + j] = l;
        }
      }
      __syncthreads();

      i32x4 a_h = *(const i32x4*)&Ah[wv * 16 + lr][lg * 8];
      i32x4 a_l = *(const i32x4*)&Al[wv * 16 + lr][lg * 8];
#pragma unroll
      for (int t = 0; t < TNT; ++t) {
        i32x4 b_h = *(const i32x4*)&Wh[t * 16 + lr][cb + lg * 8];
        i32x4 b_l = *(const i32x4*)&Wl[t * 16 + lr][cb + lg * 8];
        mfma_b16(acc[t], a_h, b_h);
        mfma_b16(acc[t], a_h, b_l);
        mfma_b16(acc[t], a_l, b_h);
      }
      __syncthreads();
    }
  }

  // cover MFMA->VALU write latency (asm is opaque to the scheduler)
  asm volatile("s_nop 7\n\ts_nop 7" ::);

#pragma unroll
  for (int t = 0; t < TNT; ++t) {
    int c = t * 16 + lr;
    float bv = bias ? bias[c] : 0.f;
#pragma unroll
    for (int q = 0; q < 4; ++q) {
      int r = row0 + wv * 16 + lg * 4 + q;
      if (r < nrows) {
        float v = acc[t][q] + bv;
        if (relu) v = fmaxf(v, 0.f);
        C[(size_t)r * BN + c] = v;
      }
    }
  }
}

// ---------------------------------------------------------------------------
// z = H @ Wnp^T + bnp  (H: [n,64], Wnp: [16,64]) then LayerNorm over 16 ch
__global__ __launch_bounds__(256) void nodepred_ln_kernel(
    const float* __restrict__ H, const float* __restrict__ Wnp, const float* __restrict__ bnp,
    const float* __restrict__ g, const float* __restrict__ lb,
    float* __restrict__ out, int nrows) {
  __shared__ float hs[16][64];
  int tid = threadIdx.x;
  int row0 = blockIdx.x * 16;
  {
    int r = tid >> 4;
    int c4 = (tid & 15) << 2;
    int gr = row0 + r;
    float4 v = make_float4(0.f, 0.f, 0.f, 0.f);
    if (gr < nrows) v = *(const float4*)(H + (size_t)gr * 64 + c4);
    *(float4*)&hs[r][c4] = v;
  }
  __syncthreads();
  int r = tid >> 4, j = tid & 15;
  float z = bnp[j];
  const float* wrow = Wnp + j * 64;
#pragma unroll 8
  for (int k = 0; k < 64; ++k) z += hs[r][k] * wrow[k];
  float s = z, s2 = z * z;
#pragma unroll
  for (int m = 1; m < 16; m <<= 1) {
    s += __shfl_xor(s, m, 16);
    s2 += __shfl_xor(s2, m, 16);
  }
  float mu = s * (1.f / 16.f);
  float var = s2 * (1.f / 16.f) - mu * mu;
  float o = (z - mu) * rsqrtf(var + EPS_LN) * g[j] + lb[j];
  int gr = row0 + r;
  if (gr < nrows) out[(size_t)gr * 16 + j] = o;
}

// ---------------------------------------------------------------------------
// out1[i] = R[mn[i]], out2[i] = X[mn[i]]   (rows of 128)
__global__ __launch_bounds__(256) void gather_out_kernel(
    const int* __restrict__ mn, const float* __restrict__ R, const float* __restrict__ X,
    float* __restrict__ o1, float* __restrict__ o2, int nmask) {
  int gid = blockIdx.x * 256 + threadIdx.x;
  if (gid >= nmask * 32) return;
  int i = gid >> 5, c4 = (gid & 31) << 2;
  int r = mn[i];
  *(float4*)(o1 + (size_t)i * 128 + c4) = *(const float4*)(R + (size_t)r * 128 + c4);
  *(float4*)(o2 + (size_t)i * 128 + c4) = *(const float4*)(X + (size_t)r * 128 + c4);
}

// ---------------------------------------------------------------------------
static void launch_gemm(const float* A1, const unsigned short* Wh1,
                        const unsigned short* Wl1, int k1,
                        const float* A2, const unsigned short* Wh2,
                        const unsigned short* Wl2, int k2,
                        const float* bias, int relu, float* C, int m, int nrows,
                        hipStream_t s) {
  int blocks = (nrows + 63) / 64;
  switch (m) {
    case 128:
      mfma_gemm_kernel<8><<<blocks, 256, 0, s>>>(A1, Wh1, Wl1, k1, A2, Wh2, Wl2, k2,
                                                 bias, relu, C, nrows);
      break;
    case 96:
      mfma_gemm_kernel<6><<<blocks, 256, 0, s>>>(A1, Wh1, Wl1, k1, A2, Wh2, Wl2, k2,
                                                 bias, relu, C, nrows);
      break;
    case 64:
      mfma_gemm_kernel<4><<<blocks, 256, 0, s>>>(A1, Wh1, Wl1, k1, A2, Wh2, Wl2, k2,
                                                 bias, relu, C, nrows);
      break;
  }
}

extern "C" void kernel_launch(void* const* d_in, const int* in_sizes, int n_in,
                              void* d_out, int out_size, void* d_ws, size_t ws_size,
                              hipStream_t stream) {
  const float* x = (const float*)d_in[0];
  const int* src = (const int*)d_in[1];
  const int* dst = (const int*)d_in[2];
  const float* ew = (const float*)d_in[3];
  const int* mn = (const int*)d_in[4];
  const float* token = (const float*)d_in[5];

  const float* W[20];
  for (int i = 0; i < 20; ++i) W[i] = (const float*)d_in[6 + i];
  const float* W_e2d = (const float*)d_in[26];
  const float* Wnp = (const float*)d_in[27];
  const float* bnp = (const float*)d_in[28];
  const float* ln_g = (const float*)d_in[29];
  const float* ln_b = (const float*)d_in[30];

  const int Nn = in_sizes[0] / 128;   // 50000
  const int E = in_sizes[1];          // 600000
  const int nmask = in_sizes[4];      // 10000
  const int nb = (Nn + SCAN_CHUNK - 1) / SCAN_CHUNK;  // 49

  // workspace layout
  float* bufA = (float*)d_ws;                      // N*128 f32
  float* bufP = bufA + (size_t)Nn * 128;           // N*128 f32
  float* bufN = bufP + (size_t)Nn * 128;           // N*128 f32
  int* deg = (int*)(bufN + (size_t)Nn * 128);      // N int
  int* cur = deg + Nn;                             // N int
  int2* esw = (int2*)(cur + Nn);                   // E int2 (8B aligned)
  int* off = (int*)(esw + E);                      // N+1 int
  int* bsum = off + Nn + 1;                        // 64 int
  int* bbase = bsum + 64;                          // 64 int
  float* WpP = (float*)(bbase + 64);               // 64*64 f32 (dec0 Wp @ W_e2d)
  float* WsP = WpP + 64 * 64;                      // 96*64 f32 (dec0 Ws @ W_e2d)
  unsigned short* wplanes =
      (unsigned short*)(((uintptr_t)(WsP + 96 * 64) + 15) & ~(uintptr_t)15);

  // ---- fold encoder_to_decoder into dec0 weights (tiny) ----
  matmul_small_kernel<<<(64 * 64 + 255) / 256, 256, 0, stream>>>(W[10], W_e2d, WpP, 64, 64, 64);
  matmul_small_kernel<<<(96 * 64 + 255) / 256, 256, 0, stream>>>(W[12], W_e2d, WsP, 96, 64, 64);

  // ---- one-shot split of all GEMM weights into bf16 hi/lo planes ----
  const int msz[12] = {128 * 128, 96 * 128, 96 * 128, 96 * 96, 64 * 96, 64 * 96,
                       64 * 64,  96 * 64,  96 * 64,  96 * 96, 128 * 96, 128 * 96};
  const float* msrc[12] = {W[0], W[2], W[3], W[5], W[7], W[8],
                           WpP,  WsP,  W[13], W[15], W[17], W[18]};
  int mtot = 0;
  int moff[12];
  for (int i = 0; i < 12; ++i) { moff[i] = mtot; mtot += msz[i]; }
  unsigned short* wh_[12];
  unsigned short* wl_[12];
  SplitWArgs sa;
  for (int i = 0; i < 12; ++i) {
    wh_[i] = wplanes + moff[i];
    wl_[i] = wplanes + mtot + moff[i];
    sa.src[i] = msrc[i];
    sa.dh[i] = wh_[i];
    sa.dl[i] = wl_[i];
    sa.n[i] = msz[i];
  }
  {
    dim3 grid((128 * 128 / 4 + 255) / 256, 12);
    split_w_kernel<<<grid, 256, 0, stream>>>(sa);
  }

  // ---- CSR build (once; graph identical across layers) ----
  hipMemsetAsync(deg, 0, (size_t)Nn * 2 * sizeof(int), stream);  // deg + cur
  hist_kernel<<<(E + 255) / 256, 256, 0, stream>>>(dst, deg, E);
  blocksum_kernel<<<nb, 256, 0, stream>>>(deg, bsum, Nn);
  bscan_kernel<<<1, 64, 0, stream>>>(bsum, bbase, off + Nn, nb);
  chunkscan_kernel<<<nb, 256, 0, stream>>>(deg, bbase, off, Nn);
  scatter_kernel<<<(E + 255) / 256, 256, 0, stream>>>(src, dst, ew, off, cur, esw, E);

  // h = x; h[mask_nodes] = token
  {
    int n4 = Nn * 128 / 4;
    copy4_kernel<<<(n4 + 255) / 256, 256, 0, stream>>>((const float4*)x, (float4*)bufA, n4);
    mask_scatter_kernel<<<(nmask * 32 + 255) / 256, 256, 0, stream>>>(mn, token, bufA, nmask);
  }

  // widx: {wp, ws, wn} plane indices per layer
  auto run_sage = [&](int ip, int is, int in_, const float* bp, const float* b,
                      int din, int dout) {
    // p = relu(h @ Wp^T + bp)
    launch_gemm(bufA, wh_[ip], wl_[ip], din, nullptr, nullptr, nullptr, 0,
                bp, 1, bufP, din, Nn, stream);
    // neigh = segment_max(p[src]*ew, dst); zero-degree rows -> 0
    int lanes = din >> 2;
    long long tot = (long long)Nn * lanes;
    int nblocks = (int)((tot + 255) / 256);
    neigh_csr_kernel<<<nblocks, 256, 0, stream>>>(bufP, off, esw, bufN, din, lanes, Nn);
    // out = relu(h @ Ws^T + neigh @ Wn^T + b)
    launch_gemm(bufA, wh_[is], wl_[is], din, bufN, wh_[in_], wl_[in_], din,
                b, 1, bufP, dout, Nn, stream);
    float* t = bufA; bufA = bufP; bufP = t;
  };

  // encoder
  run_sage(0, 1, 2, W[1], W[4], 128, 96);   // enc0
  run_sage(3, 4, 5, W[6], W[9], 96, 64);    // enc1

  // node_pred + layernorm -> n_scores (out section 3)
  float* out_r = (float*)d_out;
  float* out_x = out_r + (size_t)nmask * 128;
  float* out_ns = out_x + (size_t)nmask * 128;
  nodepred_ln_kernel<<<(Nn + 15) / 16, 256, 0, stream>>>(bufA, Wnp, bnp, ln_g, ln_b, out_ns, Nn);

  // decoder (e2d folded into dec0 weights)
  run_sage(6, 7, 8, W[11], W[14], 64, 96);     // dec0 (+e2d)
  run_sage(9, 10, 11, W[16], W[19], 96, 128);  // dec1

  // outputs 1 & 2
  gather_out_kernel<<<(nmask * 32 + 255) / 256, 256, 0, stream>>>(mn, bufA, x, out_r, out_x, nmask);
}

// Round 9
// 412.057 us; speedup vs baseline: 6.7644x; 1.1052x over previous
//
#include <hip/hip_runtime.h>

#define EPS_LN 1e-5f

typedef __attribute__((ext_vector_type(4))) float f32x4;
typedef __attribute__((ext_vector_type(4))) int i32x4;

// ---------------------------------------------------------------------------
// copy x -> H (float4 grid)
__global__ __launch_bounds__(256) void copy4_kernel(const float4* __restrict__ in,
                                                    float4* __restrict__ out, int n4) {
  int i = blockIdx.x * 256 + threadIdx.x;
  if (i < n4) out[i] = in[i];
}

// scatter mask_token into H rows listed in mn
__global__ __launch_bounds__(256) void mask_scatter_kernel(const int* __restrict__ mn,
                                                           const float* __restrict__ token,
                                                           float* __restrict__ H, int nmask) {
  int gid = blockIdx.x * 256 + threadIdx.x;
  if (gid >= nmask * 32) return;
  int i = gid >> 5;
  int c4 = (gid & 31) << 2;
  int r = mn[i];
  *(float4*)(H + (size_t)r * 128 + c4) = *(const float4*)(token + c4);
}

// ---------------------------------------------------------------------------
// CSR build: histogram of dst
__global__ __launch_bounds__(256) void hist_kernel(const int* __restrict__ dst,
                                                   int* __restrict__ deg, int nE) {
  int e = blockIdx.x * 256 + threadIdx.x;
  if (e < nE) atomicAdd(deg + dst[e], 1);
}

// ---- 3-phase parallel exclusive scan of deg[n] -> off[n+1] ----
#define SCAN_CHUNK 1024

__global__ __launch_bounds__(256) void blocksum_kernel(const int* __restrict__ deg,
                                                       int* __restrict__ bsum, int n) {
  __shared__ int red[256];
  int base = blockIdx.x * SCAN_CHUNK;
  int tid = threadIdx.x;
  int s = 0;
#pragma unroll
  for (int t = 0; t < SCAN_CHUNK / 256; ++t) {
    int g = base + tid + t * 256;
    if (g < n) s += deg[g];
  }
  red[tid] = s;
  __syncthreads();
  for (int ofs = 128; ofs > 0; ofs >>= 1) {
    if (tid < ofs) red[tid] += red[tid + ofs];
    __syncthreads();
  }
  if (tid == 0) bsum[blockIdx.x] = red[0];
}

__global__ __launch_bounds__(64) void bscan_kernel(const int* __restrict__ bsum,
                                                   int* __restrict__ bbase,
                                                   int* __restrict__ off_n, int nb) {
  int tid = threadIdx.x;
  int v = (tid < nb) ? bsum[tid] : 0;
  int incl = v;
#pragma unroll
  for (int ofs = 1; ofs < 64; ofs <<= 1) {
    int u = __shfl_up(incl, ofs, 64);
    if (tid >= ofs) incl += u;
  }
  if (tid < nb) bbase[tid] = incl - v;
  if (tid == nb - 1) off_n[0] = incl;
}

__global__ __launch_bounds__(256) void chunkscan_kernel(const int* __restrict__ deg,
                                                        const int* __restrict__ bbase,
                                                        int* __restrict__ off, int n) {
  __shared__ int part[256];
  int tid = threadIdx.x;
  int base = blockIdx.x * SCAN_CHUNK;
  int g0 = base + tid * 4;
  int loc[4];
  int s = 0;
#pragma unroll
  for (int j = 0; j < 4; ++j) {
    int g = g0 + j;
    int d = (g < n) ? deg[g] : 0;
    loc[j] = s;
    s += d;
  }
  part[tid] = s;
  __syncthreads();
  for (int ofs = 1; ofs < 256; ofs <<= 1) {
    int v = 0;
    if (tid >= ofs) v = part[tid - ofs];
    __syncthreads();
    if (tid >= ofs) part[tid] += v;
    __syncthreads();
  }
  int pre = (tid == 0) ? 0 : part[tid - 1];
  int b = bbase[blockIdx.x] + pre;
#pragma unroll
  for (int j = 0; j < 4; ++j) {
    int g = g0 + j;
    if (g < n) off[g] = b + loc[j];
  }
}

// scatter edges into dst-sorted order; (src, ew-bits) packed -> one line/edge
__global__ __launch_bounds__(256) void scatter_kernel(const int* __restrict__ src,
                                                      const int* __restrict__ dst,
                                                      const float* __restrict__ ew,
                                                      const int* __restrict__ off,
                                                      int* __restrict__ cur,
                                                      int2* __restrict__ esw, int nE) {
  int e = blockIdx.x * 256 + threadIdx.x;
  if (e >= nE) return;
  int d = dst[e];
  int pos = off[d] + atomicAdd(cur + d, 1);
  esw[pos] = make_int2(src[e], __float_as_int(ew[e]));
}

// ---------------------------------------------------------------------------
// bf16 helpers
__device__ inline unsigned short f2bf_rne(float x) {
  unsigned int u = __float_as_uint(x);
  unsigned int r = u + 0x7fffu + ((u >> 16) & 1u);
  return (unsigned short)(r >> 16);
}

__device__ inline float4 bf4_to_f4(uint2 u) {
  float4 f;
  f.x = __uint_as_float(u.x << 16);
  f.y = __uint_as_float(u.x & 0xffff0000u);
  f.z = __uint_as_float(u.y << 16);
  f.w = __uint_as_float(u.y & 0xffff0000u);
  return f;
}

// ---------------------------------------------------------------------------
// per-node segment max over CSR, bf16 P -> bf16 neigh, f32 math.
// din/4 lanes per node, one uint2 (4 bf16) per lane. 4x unrolled (4 chains).
__global__ __launch_bounds__(256) void neigh_csr_kernel(
    const unsigned short* __restrict__ P, const int* __restrict__ off,
    const int2* __restrict__ esw,
    unsigned short* __restrict__ neigh, int din, int lanes, int nN) {
  int gid = blockIdx.x * 256 + threadIdx.x;
  int v = gid / lanes;
  int c = (gid - v * lanes) << 2;
  if (v >= nN) return;
  int jlo = off[v], jhi = off[v + 1];
  float4 m0 = make_float4(0.f, 0.f, 0.f, 0.f);
  float4 m1 = m0, m2 = m0, m3 = m0;
  int j = jlo;
  for (; j + 4 <= jhi; j += 4) {
    int2 e0 = esw[j], e1 = esw[j + 1], e2 = esw[j + 2], e3 = esw[j + 3];
    uint2 q0 = *(const uint2*)(P + (size_t)e0.x * din + c);
    uint2 q1 = *(const uint2*)(P + (size_t)e1.x * din + c);
    uint2 q2 = *(const uint2*)(P + (size_t)e2.x * din + c);
    uint2 q3 = *(const uint2*)(P + (size_t)e3.x * din + c);
    float w0 = __int_as_float(e0.y), w1 = __int_as_float(e1.y);
    float w2 = __int_as_float(e2.y), w3 = __int_as_float(e3.y);
    float4 p0 = bf4_to_f4(q0), p1 = bf4_to_f4(q1);
    float4 p2 = bf4_to_f4(q2), p3 = bf4_to_f4(q3);
    m0.x = fmaxf(m0.x, p0.x * w0); m0.y = fmaxf(m0.y, p0.y * w0);
    m0.z = fmaxf(m0.z, p0.z * w0); m0.w = fmaxf(m0.w, p0.w * w0);
    m1.x = fmaxf(m1.x, p1.x * w1); m1.y = fmaxf(m1.y, p1.y * w1);
    m1.z = fmaxf(m1.z, p1.z * w1); m1.w = fmaxf(m1.w, p1.w * w1);
    m2.x = fmaxf(m2.x, p2.x * w2); m2.y = fmaxf(m2.y, p2.y * w2);
    m2.z = fmaxf(m2.z, p2.z * w2); m2.w = fmaxf(m2.w, p2.w * w2);
    m3.x = fmaxf(m3.x, p3.x * w3); m3.y = fmaxf(m3.y, p3.y * w3);
    m3.z = fmaxf(m3.z, p3.z * w3); m3.w = fmaxf(m3.w, p3.w * w3);
  }
  for (; j < jhi; ++j) {
    int2 e = esw[j];
    float w = __int_as_float(e.y);
    float4 p = bf4_to_f4(*(const uint2*)(P + (size_t)e.x * din + c));
    m0.x = fmaxf(m0.x, p.x * w); m0.y = fmaxf(m0.y, p.y * w);
    m0.z = fmaxf(m0.z, p.z * w); m0.w = fmaxf(m0.w, p.w * w);
  }
  m0.x = fmaxf(fmaxf(m0.x, m1.x), fmaxf(m2.x, m3.x));
  m0.y = fmaxf(fmaxf(m0.y, m1.y), fmaxf(m2.y, m3.y));
  m0.z = fmaxf(fmaxf(m0.z, m1.z), fmaxf(m2.z, m3.z));
  m0.w = fmaxf(fmaxf(m0.w, m1.w), fmaxf(m2.w, m3.w));
  uint2 o;
  o.x = (unsigned)f2bf_rne(m0.x) | ((unsigned)f2bf_rne(m0.y) << 16);
  o.y = (unsigned)f2bf_rne(m0.z) | ((unsigned)f2bf_rne(m0.w) << 16);
  *(uint2*)(neigh + (size_t)v * din + c) = o;
}

// ---------------------------------------------------------------------------
// small weight-combine: C[M][N] = A[M][K] @ B[K][N]  (row-major, tiny)
__global__ __launch_bounds__(256) void matmul_small_kernel(const float* __restrict__ A,
                                                           const float* __restrict__ B,
                                                           float* __restrict__ C,
                                                           int M, int K, int N) {
  int idx = blockIdx.x * 256 + threadIdx.x;
  if (idx >= M * N) return;
  int o = idx / N, i = idx - o * N;
  float s = 0.f;
  for (int k = 0; k < K; ++k) s += A[o * K + k] * B[k * N + i];
  C[idx] = s;
}

// ---------------------------------------------------------------------------
// split helpers
__device__ inline void mfma_b16(f32x4& acc, i32x4 a, i32x4 b) {
  asm volatile("v_mfma_f32_16x16x32_bf16 %0, %1, %2, %0"
               : "+v"(acc)
               : "v"(a), "v"(b));
}

__device__ inline void split_bf16(float x, unsigned short& hi, unsigned short& lo) {
  unsigned int bits = __float_as_uint(x);
  hi = (unsigned short)(bits >> 16);
  float hif = __uint_as_float((unsigned int)hi << 16);
  float res = x - hif;
  lo = (unsigned short)(__float_as_uint(res) >> 16);
}

// one-shot split of all weight matrices into bf16 hi/lo planes
struct SplitWArgs {
  const float* src[12];
  unsigned short* dh[12];
  unsigned short* dl[12];
  int n[12];
};

__global__ __launch_bounds__(256) void split_w_kernel(SplitWArgs a) {
  int m = blockIdx.y;
  int i = (blockIdx.x * 256 + threadIdx.x) * 4;
  if (i >= a.n[m]) return;
  float4 v = *(const float4*)(a.src[m] + i);
  unsigned short h[4], l[4];
  split_bf16(v.x, h[0], l[0]);
  split_bf16(v.y, h[1], l[1]);
  split_bf16(v.z, h[2], l[2]);
  split_bf16(v.w, h[3], l[3]);
  *(uint2*)(a.dh[m] + i) = make_uint2((unsigned)h[0] | ((unsigned)h[1] << 16),
                                      (unsigned)h[2] | ((unsigned)h[3] << 16));
  *(uint2*)(a.dl[m] + i) = make_uint2((unsigned)l[0] | ((unsigned)l[1] << 16),
                                      (unsigned)l[2] | ((unsigned)l[3] << 16));
}

// ---------------------------------------------------------------------------
// MFMA split-bf16 GEMM: C[nrows, BN] = act( A1@W1^T (+ A2b@W2^T) (+bias) )
// Pass 0: A1 f32, split on the fly, 3-term MFMA (hh+hl+lh).
// Pass 1: A2b bf16 (neigh), direct LDS copy, 2-term MFMA (ah*bh + ah*bl).
// W pre-split global hi/lo planes (pure LDS copy).
// Block: 256 thr = 4 waves; tile 64 rows x BN; wave w owns rows w*16..w*16+15.
// v_mfma_f32_16x16x32_bf16: A[row=lane&15][k=8*(lane>>4)+e],
//                           B[k=8*(lane>>4)+e][col=lane&15],
//                           D[row=4*(lane>>4)+q][col=lane&15].
template <int TNT>  // BN = TNT*16
__global__ __launch_bounds__(256) void mfma_gemm_kernel(
    const float* __restrict__ A1, const unsigned short* __restrict__ Wh1,
    const unsigned short* __restrict__ Wl1, int k1,
    const unsigned short* __restrict__ A2b, const unsigned short* __restrict__ Wh2,
    const unsigned short* __restrict__ Wl2, int k2,
    const float* __restrict__ bias, int relu, int out_bf16,
    void* __restrict__ Cv, int nrows) {
  constexpr int BN = TNT * 16;
  constexpr int WS = 136;  // W LDS row stride (ushort)
  constexpr int AS = 40;   // A LDS row stride (ushort)
  __shared__ __align__(16) unsigned short Wh[BN][WS];
  __shared__ __align__(16) unsigned short Wl[BN][WS];
  __shared__ __align__(16) unsigned short Ah[64][AS];
  __shared__ __align__(16) unsigned short Al[64][AS];

  const int tid = threadIdx.x;
  const int lane = tid & 63;
  const int wv = tid >> 6;      // wave 0..3 -> row band wv*16
  const int lr = lane & 15;     // frag row (A) / col (B,D)
  const int lg = lane >> 4;     // k-granule 0..3
  const int row0 = blockIdx.x * 64;

  f32x4 acc[TNT];
#pragma unroll
  for (int t = 0; t < TNT; ++t) acc[t] = (f32x4)(0.f);

  for (int pass = 0; pass < 2; ++pass) {
    if (pass && A2b == nullptr) continue;
    const unsigned short* Whp = pass ? Wh2 : Wh1;
    const unsigned short* Wlp = pass ? Wl2 : Wl1;
    const int K = pass ? k2 : k1;

    // copy pre-split W planes (BN x K ushort each) into LDS, 16B chunks
    {
      int tot8 = BN * K / 8;
      for (int i = tid; i < tot8; i += 256) {
        int e0 = i * 8;
        int col = e0 / K;
        int kk = e0 - col * K;
        *(uint4*)&Wh[col][kk] = *(const uint4*)(Whp + e0);
        *(uint4*)&Wl[col][kk] = *(const uint4*)(Wlp + e0);
      }
    }

    for (int cb = 0; cb < K; cb += 32) {
      if (pass == 0) {
        // stage A chunk: 64 rows x 32 k f32, convert to hi/lo
        int r = tid >> 2;
        int k0 = (tid & 3) * 8;
        int gr = row0 + r;
        float4 v0 = make_float4(0.f, 0.f, 0.f, 0.f);
        float4 v1 = make_float4(0.f, 0.f, 0.f, 0.f);
        if (gr < nrows) {
          const float* ap = A1 + (size_t)gr * K + cb + k0;
          v0 = *(const float4*)ap;
          v1 = *(const float4*)(ap + 4);
        }
        float vv[8] = {v0.x, v0.y, v0.z, v0.w, v1.x, v1.y, v1.z, v1.w};
#pragma unroll
        for (int j = 0; j < 8; ++j) {
          unsigned short h, l;
          split_bf16(vv[j], h, l);
          Ah[r][k0 + j] = h;
          Al[r][k0 + j] = l;
        }
      } else {
        // stage bf16 A chunk: 64 rows x 32 k ushort, pure copy (1 uint4/thread)
        int r = tid >> 2;
        int k0 = (tid & 3) * 8;
        int gr = row0 + r;
        uint4 vv = make_uint4(0, 0, 0, 0);
        if (gr < nrows) vv = *(const uint4*)(A2b + (size_t)gr * K + cb + k0);
        *(uint4*)&Ah[r][k0] = vv;
      }
      __syncthreads();

      i32x4 a_h = *(const i32x4*)&Ah[wv * 16 + lr][lg * 8];
      i32x4 a_l = a_h;
      if (pass == 0) a_l = *(const i32x4*)&Al[wv * 16 + lr][lg * 8];
#pragma unroll
      for (int t = 0; t < TNT; ++t) {
        i32x4 b_h = *(const i32x4*)&Wh[t * 16 + lr][cb + lg * 8];
        i32x4 b_l = *(const i32x4*)&Wl[t * 16 + lr][cb + lg * 8];
        mfma_b16(acc[t], a_h, b_h);
        mfma_b16(acc[t], a_h, b_l);
        if (pass == 0) mfma_b16(acc[t], a_l, b_h);
      }
      __syncthreads();
    }
  }

  // cover MFMA->VALU write latency (asm is opaque to the scheduler)
  asm volatile("s_nop 7\n\ts_nop 7" ::);

#pragma unroll
  for (int t = 0; t < TNT; ++t) {
    int c = t * 16 + lr;
    float bv = bias ? bias[c] : 0.f;
#pragma unroll
    for (int q = 0; q < 4; ++q) {
      int r = row0 + wv * 16 + lg * 4 + q;
      if (r < nrows) {
        float v = acc[t][q] + bv;
        if (relu) v = fmaxf(v, 0.f);
        if (out_bf16)
          ((unsigned short*)Cv)[(size_t)r * BN + c] = f2bf_rne(v);
        else
          ((float*)Cv)[(size_t)r * BN + c] = v;
      }
    }
  }
}

// ---------------------------------------------------------------------------
// z = H @ Wnp^T + bnp  (H: [n,64], Wnp: [16,64]) then LayerNorm over 16 ch
__global__ __launch_bounds__(256) void nodepred_ln_kernel(
    const float* __restrict__ H, const float* __restrict__ Wnp, const float* __restrict__ bnp,
    const float* __restrict__ g, const float* __restrict__ lb,
    float* __restrict__ out, int nrows) {
  __shared__ float hs[16][64];
  int tid = threadIdx.x;
  int row0 = blockIdx.x * 16;
  {
    int r = tid >> 4;
    int c4 = (tid & 15) << 2;
    int gr = row0 + r;
    float4 v = make_float4(0.f, 0.f, 0.f, 0.f);
    if (gr < nrows) v = *(const float4*)(H + (size_t)gr * 64 + c4);
    *(float4*)&hs[r][c4] = v;
  }
  __syncthreads();
  int r = tid >> 4, j = tid & 15;
  float z = bnp[j];
  const float* wrow = Wnp + j * 64;
#pragma unroll 8
  for (int k = 0; k < 64; ++k) z += hs[r][k] * wrow[k];
  float s = z, s2 = z * z;
#pragma unroll
  for (int m = 1; m < 16; m <<= 1) {
    s += __shfl_xor(s, m, 16);
    s2 += __shfl_xor(s2, m, 16);
  }
  float mu = s * (1.f / 16.f);
  float var = s2 * (1.f / 16.f) - mu * mu;
  float o = (z - mu) * rsqrtf(var + EPS_LN) * g[j] + lb[j];
  int gr = row0 + r;
  if (gr < nrows) out[(size_t)gr * 16 + j] = o;
}

// ---------------------------------------------------------------------------
// out1[i] = R[mn[i]], out2[i] = X[mn[i]]   (rows of 128)
__global__ __launch_bounds__(256) void gather_out_kernel(
    const int* __restrict__ mn, const float* __restrict__ R, const float* __restrict__ X,
    float* __restrict__ o1, float* __restrict__ o2, int nmask) {
  int gid = blockIdx.x * 256 + threadIdx.x;
  if (gid >= nmask * 32) return;
  int i = gid >> 5, c4 = (gid & 31) << 2;
  int r = mn[i];
  *(float4*)(o1 + (size_t)i * 128 + c4) = *(const float4*)(R + (size_t)r * 128 + c4);
  *(float4*)(o2 + (size_t)i * 128 + c4) = *(const float4*)(X + (size_t)r * 128 + c4);
}

// ---------------------------------------------------------------------------
static void launch_gemm(const float* A1, const unsigned short* Wh1,
                        const unsigned short* Wl1, int k1,
                        const unsigned short* A2b, const unsigned short* Wh2,
                        const unsigned short* Wl2, int k2,
                        const float* bias, int relu, int out_bf16,
                        void* C, int m, int nrows, hipStream_t s) {
  int blocks = (nrows + 63) / 64;
  switch (m) {
    case 128:
      mfma_gemm_kernel<8><<<blocks, 256, 0, s>>>(A1, Wh1, Wl1, k1, A2b, Wh2, Wl2, k2,
                                                 bias, relu, out_bf16, C, nrows);
      break;
    case 96:
      mfma_gemm_kernel<6><<<blocks, 256, 0, s>>>(A1, Wh1, Wl1, k1, A2b, Wh2, Wl2, k2,
                                                 bias, relu, out_bf16, C, nrows);
      break;
    case 64:
      mfma_gemm_kernel<4><<<blocks, 256, 0, s>>>(A1, Wh1, Wl1, k1, A2b, Wh2, Wl2, k2,
                                                 bias, relu, out_bf16, C, nrows);
      break;
  }
}

extern "C" void kernel_launch(void* const* d_in, const int* in_sizes, int n_in,
                              void* d_out, int out_size, void* d_ws, size_t ws_size,
                              hipStream_t stream) {
  const float* x = (const float*)d_in[0];
  const int* src = (const int*)d_in[1];
  const int* dst = (const int*)d_in[2];
  const float* ew = (const float*)d_in[3];
  const int* mn = (const int*)d_in[4];
  const float* token = (const float*)d_in[5];

  const float* W[20];
  for (int i = 0; i < 20; ++i) W[i] = (const float*)d_in[6 + i];
  const float* W_e2d = (const float*)d_in[26];
  const float* Wnp = (const float*)d_in[27];
  const float* bnp = (const float*)d_in[28];
  const float* ln_g = (const float*)d_in[29];
  const float* ln_b = (const float*)d_in[30];

  const int Nn = in_sizes[0] / 128;   // 50000
  const int E = in_sizes[1];          // 600000
  const int nmask = in_sizes[4];      // 10000
  const int nb = (Nn + SCAN_CHUNK - 1) / SCAN_CHUNK;  // 49

  // workspace layout
  float* bufA = (float*)d_ws;                              // N*128 f32
  float* bufB = bufA + (size_t)Nn * 128;                   // N*128 f32
  unsigned short* pool16 = (unsigned short*)(bufB + (size_t)Nn * 128);  // N*128 bf16
  unsigned short* neigh16 = pool16 + (size_t)Nn * 128;     // N*128 bf16
  int* deg = (int*)(neigh16 + (size_t)Nn * 128);           // N int
  int* cur = deg + Nn;                                     // N int
  int2* esw = (int2*)(cur + Nn);                           // E int2
  int* off = (int*)(esw + E);                              // N+1 int
  int* bsum = off + Nn + 1;                                // 64 int
  int* bbase = bsum + 64;                                  // 64 int
  float* WpP = (float*)(bbase + 64);                       // 64*64 f32
  float* WsP = WpP + 64 * 64;                              // 96*64 f32
  unsigned short* wplanes =
      (unsigned short*)(((uintptr_t)(WsP + 96 * 64) + 15) & ~(uintptr_t)15);

  // ---- fold encoder_to_decoder into dec0 weights (tiny) ----
  matmul_small_kernel<<<(64 * 64 + 255) / 256, 256, 0, stream>>>(W[10], W_e2d, WpP, 64, 64, 64);
  matmul_small_kernel<<<(96 * 64 + 255) / 256, 256, 0, stream>>>(W[12], W_e2d, WsP, 96, 64, 64);

  // ---- one-shot split of all GEMM weights into bf16 hi/lo planes ----
  const int msz[12] = {128 * 128, 96 * 128, 96 * 128, 96 * 96, 64 * 96, 64 * 96,
                       64 * 64,  96 * 64,  96 * 64,  96 * 96, 128 * 96, 128 * 96};
  const float* msrc[12] = {W[0], W[2], W[3], W[5], W[7], W[8],
                           WpP,  WsP,  W[13], W[15], W[17], W[18]};
  int mtot = 0;
  int moff[12];
  for (int i = 0; i < 12; ++i) { moff[i] = mtot; mtot += msz[i]; }
  unsigned short* wh_[12];
  unsigned short* wl_[12];
  SplitWArgs sa;
  for (int i = 0; i < 12; ++i) {
    wh_[i] = wplanes + moff[i];
    wl_[i] = wplanes + mtot + moff[i];
    sa.src[i] = msrc[i];
    sa.dh[i] = wh_[i];
    sa.dl[i] = wl_[i];
    sa.n[i] = msz[i];
  }
  {
    dim3 grid((128 * 128 / 4 + 255) / 256, 12);
    split_w_kernel<<<grid, 256, 0, stream>>>(sa);
  }

  // ---- CSR build (once; graph identical across layers) ----
  hipMemsetAsync(deg, 0, (size_t)Nn * 2 * sizeof(int), stream);  // deg + cur
  hist_kernel<<<(E + 255) / 256, 256, 0, stream>>>(dst, deg, E);
  blocksum_kernel<<<nb, 256, 0, stream>>>(deg, bsum, Nn);
  bscan_kernel<<<1, 64, 0, stream>>>(bsum, bbase, off + Nn, nb);
  chunkscan_kernel<<<nb, 256, 0, stream>>>(deg, bbase, off, Nn);
  scatter_kernel<<<(E + 255) / 256, 256, 0, stream>>>(src, dst, ew, off, cur, esw, E);

  // h = x; h[mask_nodes] = token
  {
    int n4 = Nn * 128 / 4;
    copy4_kernel<<<(n4 + 255) / 256, 256, 0, stream>>>((const float4*)x, (float4*)bufA, n4);
    mask_scatter_kernel<<<(nmask * 32 + 255) / 256, 256, 0, stream>>>(mn, token, bufA, nmask);
  }

  // plane indices {wp, ws, wn} per layer
  auto run_sage = [&](int ip, int is, int in_, const float* bp, const float* b,
                      int din, int dout) {
    // p = relu(h @ Wp^T + bp)  -> bf16 pool
    launch_gemm(bufA, wh_[ip], wl_[ip], din, nullptr, nullptr, nullptr, 0,
                bp, 1, 1, pool16, din, Nn, stream);
    // neigh = segment_max(p[src]*ew, dst), bf16 -> bf16; zero-degree rows -> 0
    int lanes = din >> 2;
    long long tot = (long long)Nn * lanes;
    int nblocks = (int)((tot + 255) / 256);
    neigh_csr_kernel<<<nblocks, 256, 0, stream>>>(pool16, off, esw, neigh16, din, lanes, Nn);
    // out = relu(h @ Ws^T + neigh @ Wn^T + b)  (f32 out)
    launch_gemm(bufA, wh_[is], wl_[is], din, neigh16, wh_[in_], wl_[in_], din,
                b, 1, 0, bufB, dout, Nn, stream);
    float* t = bufA; bufA = bufB; bufB = t;
  };

  // encoder
  run_sage(0, 1, 2, W[1], W[4], 128, 96);   // enc0
  run_sage(3, 4, 5, W[6], W[9], 96, 64);    // enc1

  // node_pred + layernorm -> n_scores (out section 3)
  float* out_r = (float*)d_out;
  float* out_x = out_r + (size_t)nmask * 128;
  float* out_ns = out_x + (size_t)nmask * 128;
  nodepred_ln_kernel<<<(Nn + 15) / 16, 256, 0, stream>>>(bufA, Wnp, bnp, ln_g, ln_b, out_ns, Nn);

  // decoder (e2d folded into dec0 weights)
  run_sage(6, 7, 8, W[11], W[14], 64, 96);     // dec0 (+e2d)
  run_sage(9, 10, 11, W[16], W[19], 96, 128);  // dec1

  // outputs 1 & 2
  gather_out_kernel<<<(nmask * 32 + 255) / 256, 256, 0, stream>>>(mn, bufA, x, out_r, out_x, nmask);
}

// Round 10
// 378.126 us; speedup vs baseline: 7.3714x; 1.0897x over previous
//
#include <hip/hip_runtime.h>

#define EPS_LN 1e-5f

typedef __attribute__((ext_vector_type(4))) float f32x4;
typedef __attribute__((ext_vector_type(4))) int i32x4;

// ---------------------------------------------------------------------------
// bf16 helpers
__device__ inline unsigned short f2bf_rne(float x) {
  unsigned int u = __float_as_uint(x);
  unsigned int r = u + 0x7fffu + ((u >> 16) & 1u);
  return (unsigned short)(r >> 16);
}

__device__ inline float4 bf4_to_f4(uint2 u) {
  float4 f;
  f.x = __uint_as_float(u.x << 16);
  f.y = __uint_as_float(u.x & 0xffff0000u);
  f.z = __uint_as_float(u.y << 16);
  f.w = __uint_as_float(u.y & 0xffff0000u);
  return f;
}

__device__ inline uint2 f4_to_bf4(float4 v) {
  uint2 o;
  o.x = (unsigned)f2bf_rne(v.x) | ((unsigned)f2bf_rne(v.y) << 16);
  o.y = (unsigned)f2bf_rne(v.z) | ((unsigned)f2bf_rne(v.w) << 16);
  return o;
}

// ---------------------------------------------------------------------------
// x (f32) -> H (bf16)
__global__ __launch_bounds__(256) void copy_bf16_kernel(const float4* __restrict__ in,
                                                        uint2* __restrict__ out, int n4) {
  int i = blockIdx.x * 256 + threadIdx.x;
  if (i < n4) out[i] = f4_to_bf4(in[i]);
}

// scatter mask_token (f32) into bf16 H rows listed in mn
__global__ __launch_bounds__(256) void mask_scatter_kernel(const int* __restrict__ mn,
                                                           const float* __restrict__ token,
                                                           unsigned short* __restrict__ H,
                                                           int nmask) {
  int gid = blockIdx.x * 256 + threadIdx.x;
  if (gid >= nmask * 32) return;
  int i = gid >> 5;
  int c4 = (gid & 31) << 2;
  int r = mn[i];
  float4 t = *(const float4*)(token + c4);
  *(uint2*)(H + (size_t)r * 128 + c4) = f4_to_bf4(t);
}

// ---------------------------------------------------------------------------
// CSR build: histogram of dst
__global__ __launch_bounds__(256) void hist_kernel(const int* __restrict__ dst,
                                                   int* __restrict__ deg, int nE) {
  int e = blockIdx.x * 256 + threadIdx.x;
  if (e < nE) atomicAdd(deg + dst[e], 1);
}

// ---- 3-phase parallel exclusive scan of deg[n] -> off[n+1] ----
#define SCAN_CHUNK 1024

__global__ __launch_bounds__(256) void blocksum_kernel(const int* __restrict__ deg,
                                                       int* __restrict__ bsum, int n) {
  __shared__ int red[256];
  int base = blockIdx.x * SCAN_CHUNK;
  int tid = threadIdx.x;
  int s = 0;
#pragma unroll
  for (int t = 0; t < SCAN_CHUNK / 256; ++t) {
    int g = base + tid + t * 256;
    if (g < n) s += deg[g];
  }
  red[tid] = s;
  __syncthreads();
  for (int ofs = 128; ofs > 0; ofs >>= 1) {
    if (tid < ofs) red[tid] += red[tid + ofs];
    __syncthreads();
  }
  if (tid == 0) bsum[blockIdx.x] = red[0];
}

__global__ __launch_bounds__(64) void bscan_kernel(const int* __restrict__ bsum,
                                                   int* __restrict__ bbase,
                                                   int* __restrict__ off_n, int nb) {
  int tid = threadIdx.x;
  int v = (tid < nb) ? bsum[tid] : 0;
  int incl = v;
#pragma unroll
  for (int ofs = 1; ofs < 64; ofs <<= 1) {
    int u = __shfl_up(incl, ofs, 64);
    if (tid >= ofs) incl += u;
  }
  if (tid < nb) bbase[tid] = incl - v;
  if (tid == nb - 1) off_n[0] = incl;
}

__global__ __launch_bounds__(256) void chunkscan_kernel(const int* __restrict__ deg,
                                                        const int* __restrict__ bbase,
                                                        int* __restrict__ off, int n) {
  __shared__ int part[256];
  int tid = threadIdx.x;
  int base = blockIdx.x * SCAN_CHUNK;
  int g0 = base + tid * 4;
  int loc[4];
  int s = 0;
#pragma unroll
  for (int j = 0; j < 4; ++j) {
    int g = g0 + j;
    int d = (g < n) ? deg[g] : 0;
    loc[j] = s;
    s += d;
  }
  part[tid] = s;
  __syncthreads();
  for (int ofs = 1; ofs < 256; ofs <<= 1) {
    int v = 0;
    if (tid >= ofs) v = part[tid - ofs];
    __syncthreads();
    if (tid >= ofs) part[tid] += v;
    __syncthreads();
  }
  int pre = (tid == 0) ? 0 : part[tid - 1];
  int b = bbase[blockIdx.x] + pre;
#pragma unroll
  for (int j = 0; j < 4; ++j) {
    int g = g0 + j;
    if (g < n) off[g] = b + loc[j];
  }
}

// scatter edges into dst-sorted order; (src, ew-bits) packed -> one line/edge
__global__ __launch_bounds__(256) void scatter_kernel(const int* __restrict__ src,
                                                      const int* __restrict__ dst,
                                                      const float* __restrict__ ew,
                                                      const int* __restrict__ off,
                                                      int* __restrict__ cur,
                                                      int2* __restrict__ esw, int nE) {
  int e = blockIdx.x * 256 + threadIdx.x;
  if (e >= nE) return;
  int d = dst[e];
  int pos = off[d] + atomicAdd(cur + d, 1);
  esw[pos] = make_int2(src[e], __float_as_int(ew[e]));
}

// ---------------------------------------------------------------------------
// per-node segment max over CSR, bf16 P -> bf16 neigh, f32 math.
// din/4 lanes per node, one uint2 (4 bf16) per lane. 4x unrolled (4 chains).
__global__ __launch_bounds__(256) void neigh_csr_kernel(
    const unsigned short* __restrict__ P, const int* __restrict__ off,
    const int2* __restrict__ esw,
    unsigned short* __restrict__ neigh, int din, int lanes, int nN) {
  int gid = blockIdx.x * 256 + threadIdx.x;
  int v = gid / lanes;
  int c = (gid - v * lanes) << 2;
  if (v >= nN) return;
  int jlo = off[v], jhi = off[v + 1];
  float4 m0 = make_float4(0.f, 0.f, 0.f, 0.f);
  float4 m1 = m0, m2 = m0, m3 = m0;
  int j = jlo;
  for (; j + 4 <= jhi; j += 4) {
    int2 e0 = esw[j], e1 = esw[j + 1], e2 = esw[j + 2], e3 = esw[j + 3];
    uint2 q0 = *(const uint2*)(P + (size_t)e0.x * din + c);
    uint2 q1 = *(const uint2*)(P + (size_t)e1.x * din + c);
    uint2 q2 = *(const uint2*)(P + (size_t)e2.x * din + c);
    uint2 q3 = *(const uint2*)(P + (size_t)e3.x * din + c);
    float w0 = __int_as_float(e0.y), w1 = __int_as_float(e1.y);
    float w2 = __int_as_float(e2.y), w3 = __int_as_float(e3.y);
    float4 p0 = bf4_to_f4(q0), p1 = bf4_to_f4(q1);
    float4 p2 = bf4_to_f4(q2), p3 = bf4_to_f4(q3);
    m0.x = fmaxf(m0.x, p0.x * w0); m0.y = fmaxf(m0.y, p0.y * w0);
    m0.z = fmaxf(m0.z, p0.z * w0); m0.w = fmaxf(m0.w, p0.w * w0);
    m1.x = fmaxf(m1.x, p1.x * w1); m1.y = fmaxf(m1.y, p1.y * w1);
    m1.z = fmaxf(m1.z, p1.z * w1); m1.w = fmaxf(m1.w, p1.w * w1);
    m2.x = fmaxf(m2.x, p2.x * w2); m2.y = fmaxf(m2.y, p2.y * w2);
    m2.z = fmaxf(m2.z, p2.z * w2); m2.w = fmaxf(m2.w, p2.w * w2);
    m3.x = fmaxf(m3.x, p3.x * w3); m3.y = fmaxf(m3.y, p3.y * w3);
    m3.z = fmaxf(m3.z, p3.z * w3); m3.w = fmaxf(m3.w, p3.w * w3);
  }
  for (; j < jhi; ++j) {
    int2 e = esw[j];
    float w = __int_as_float(e.y);
    float4 p = bf4_to_f4(*(const uint2*)(P + (size_t)e.x * din + c));
    m0.x = fmaxf(m0.x, p.x * w); m0.y = fmaxf(m0.y, p.y * w);
    m0.z = fmaxf(m0.z, p.z * w); m0.w = fmaxf(m0.w, p.w * w);
  }
  m0.x = fmaxf(fmaxf(m0.x, m1.x), fmaxf(m2.x, m3.x));
  m0.y = fmaxf(fmaxf(m0.y, m1.y), fmaxf(m2.y, m3.y));
  m0.z = fmaxf(fmaxf(m0.z, m1.z), fmaxf(m2.z, m3.z));
  m0.w = fmaxf(fmaxf(m0.w, m1.w), fmaxf(m2.w, m3.w));
  float4 mm = make_float4(m0.x, m0.y, m0.z, m0.w);
  *(uint2*)(neigh + (size_t)v * din + c) = f4_to_bf4(mm);
}

// ---------------------------------------------------------------------------
// small weight-combine: C[M][N] = A[M][K] @ B[K][N]  (row-major, tiny)
__global__ __launch_bounds__(256) void matmul_small_kernel(const float* __restrict__ A,
                                                           const float* __restrict__ B,
                                                           float* __restrict__ C,
                                                           int M, int K, int N) {
  int idx = blockIdx.x * 256 + threadIdx.x;
  if (idx >= M * N) return;
  int o = idx / N, i = idx - o * N;
  float s = 0.f;
  for (int k = 0; k < K; ++k) s += A[o * K + k] * B[k * N + i];
  C[idx] = s;
}

// ---------------------------------------------------------------------------
__device__ inline void mfma_b16(f32x4& acc, i32x4 a, i32x4 b) {
  asm volatile("v_mfma_f32_16x16x32_bf16 %0, %1, %2, %0"
               : "+v"(acc)
               : "v"(a), "v"(b));
}

__device__ inline void split_bf16(float x, unsigned short& hi, unsigned short& lo) {
  unsigned int bits = __float_as_uint(x);
  hi = (unsigned short)(bits >> 16);
  float hif = __uint_as_float((unsigned int)hi << 16);
  float res = x - hif;
  lo = (unsigned short)(__float_as_uint(res) >> 16);
}

// one-shot split of all weight matrices into bf16 hi/lo planes
struct SplitWArgs {
  const float* src[12];
  unsigned short* dh[12];
  unsigned short* dl[12];
  int n[12];
};

__global__ __launch_bounds__(256) void split_w_kernel(SplitWArgs a) {
  int m = blockIdx.y;
  int i = (blockIdx.x * 256 + threadIdx.x) * 4;
  if (i >= a.n[m]) return;
  float4 v = *(const float4*)(a.src[m] + i);
  unsigned short h[4], l[4];
  split_bf16(v.x, h[0], l[0]);
  split_bf16(v.y, h[1], l[1]);
  split_bf16(v.z, h[2], l[2]);
  split_bf16(v.w, h[3], l[3]);
  *(uint2*)(a.dh[m] + i) = make_uint2((unsigned)h[0] | ((unsigned)h[1] << 16),
                                      (unsigned)h[2] | ((unsigned)h[3] << 16));
  *(uint2*)(a.dl[m] + i) = make_uint2((unsigned)l[0] | ((unsigned)l[1] << 16),
                                      (unsigned)l[2] | ((unsigned)l[3] << 16));
}

// ---------------------------------------------------------------------------
// MFMA GEMM, bf16 activations: C_bf16[nrows,BN] = act( A1@W1^T (+A2@W2^T) +bias )
// A bf16 in global, fragments loaded DIRECTLY from global (no A staging).
// W pre-split hi/lo planes in LDS; 2-term MFMA (a*Wh + a*Wl) keeps W ~f32.
// Block: 256 thr = 4 waves; tile 64 rows x BN; wave w owns rows w*16..w*16+15.
// v_mfma_f32_16x16x32_bf16: A[row=lane&15][k=8*(lane>>4)+e],
//                           B[k=8*(lane>>4)+e][col=lane&15],
//                           D[row=4*(lane>>4)+q][col=lane&15].
template <int TNT>  // BN = TNT*16
__global__ __launch_bounds__(256) void mfma_gemm_kernel(
    const unsigned short* __restrict__ A1, const unsigned short* __restrict__ Wh1,
    const unsigned short* __restrict__ Wl1, int k1,
    const unsigned short* __restrict__ A2, const unsigned short* __restrict__ Wh2,
    const unsigned short* __restrict__ Wl2, int k2,
    const float* __restrict__ bias, int relu,
    unsigned short* __restrict__ C, int nrows) {
  constexpr int BN = TNT * 16;
  constexpr int WS = 136;  // W LDS row stride (ushort)
  __shared__ __align__(16) unsigned short Wh[BN][WS];
  __shared__ __align__(16) unsigned short Wl[BN][WS];

  const int tid = threadIdx.x;
  const int lane = tid & 63;
  const int wv = tid >> 6;      // wave 0..3 -> row band wv*16
  const int lr = lane & 15;     // frag row (A) / col (B,D)
  const int lg = lane >> 4;     // k-granule 0..3
  const int row0 = blockIdx.x * 64;
  const int gra = row0 + wv * 16 + lr;   // this lane's A row

  f32x4 acc[TNT];
#pragma unroll
  for (int t = 0; t < TNT; ++t) acc[t] = (f32x4)(0.f);

  for (int pass = 0; pass < 2; ++pass) {
    const unsigned short* A = pass ? A2 : A1;
    if (A == nullptr) continue;  // uniform across block
    const unsigned short* Whp = pass ? Wh2 : Wh1;
    const unsigned short* Wlp = pass ? Wl2 : Wl1;
    const int K = pass ? k2 : k1;

    if (pass) __syncthreads();  // protect previous pass's W reads
    {
      int tot8 = BN * K / 8;
      for (int i = tid; i < tot8; i += 256) {
        int e0 = i * 8;
        int col = e0 / K;
        int kk = e0 - col * K;
        *(uint4*)&Wh[col][kk] = *(const uint4*)(Whp + e0);
        *(uint4*)&Wl[col][kk] = *(const uint4*)(Wlp + e0);
      }
    }
    __syncthreads();

    for (int cb = 0; cb < K; cb += 32) {
      i32x4 a_h = (i32x4)(0);
      if (gra < nrows) a_h = *(const i32x4*)(A + (size_t)gra * K + cb + lg * 8);
#pragma unroll
      for (int t = 0; t < TNT; ++t) {
        i32x4 b_h = *(const i32x4*)&Wh[t * 16 + lr][cb + lg * 8];
        i32x4 b_l = *(const i32x4*)&Wl[t * 16 + lr][cb + lg * 8];
        mfma_b16(acc[t], a_h, b_h);
        mfma_b16(acc[t], a_h, b_l);
      }
    }
  }

  // cover MFMA->VALU write latency (asm is opaque to the scheduler)
  asm volatile("s_nop 7\n\ts_nop 7" ::);

#pragma unroll
  for (int t = 0; t < TNT; ++t) {
    int c = t * 16 + lr;
    float bv = bias ? bias[c] : 0.f;
#pragma unroll
    for (int q = 0; q < 4; ++q) {
      int r = row0 + wv * 16 + lg * 4 + q;
      if (r < nrows) {
        float v = acc[t][q] + bv;
        if (relu) v = fmaxf(v, 0.f);
        C[(size_t)r * BN + c] = f2bf_rne(v);
      }
    }
  }
}

// ---------------------------------------------------------------------------
// z = H @ Wnp^T + bnp  (H: [n,64] bf16, Wnp: [16,64] f32) then LayerNorm(16)
__global__ __launch_bounds__(256) void nodepred_ln_kernel(
    const unsigned short* __restrict__ H, const float* __restrict__ Wnp,
    const float* __restrict__ bnp, const float* __restrict__ g,
    const float* __restrict__ lb, float* __restrict__ out, int nrows) {
  __shared__ float hs[16][64];
  int tid = threadIdx.x;
  int row0 = blockIdx.x * 16;
  {
    int r = tid >> 4;
    int c4 = (tid & 15) << 2;
    int gr = row0 + r;
    float4 v = make_float4(0.f, 0.f, 0.f, 0.f);
    if (gr < nrows) v = bf4_to_f4(*(const uint2*)(H + (size_t)gr * 64 + c4));
    *(float4*)&hs[r][c4] = v;
  }
  __syncthreads();
  int r = tid >> 4, j = tid & 15;
  float z = bnp[j];
  const float* wrow = Wnp + j * 64;
#pragma unroll 8
  for (int k = 0; k < 64; ++k) z += hs[r][k] * wrow[k];
  float s = z, s2 = z * z;
#pragma unroll
  for (int m = 1; m < 16; m <<= 1) {
    s += __shfl_xor(s, m, 16);
    s2 += __shfl_xor(s2, m, 16);
  }
  float mu = s * (1.f / 16.f);
  float var = s2 * (1.f / 16.f) - mu * mu;
  float o = (z - mu) * rsqrtf(var + EPS_LN) * g[j] + lb[j];
  int gr = row0 + r;
  if (gr < nrows) out[(size_t)gr * 16 + j] = o;
}

// ---------------------------------------------------------------------------
// out1[i] = f32(R_bf16[mn[i]]), out2[i] = X_f32[mn[i]]   (rows of 128)
__global__ __launch_bounds__(256) void gather_out_kernel(
    const int* __restrict__ mn, const unsigned short* __restrict__ R,
    const float* __restrict__ X,
    float* __restrict__ o1, float* __restrict__ o2, int nmask) {
  int gid = blockIdx.x * 256 + threadIdx.x;
  if (gid >= nmask * 32) return;
  int i = gid >> 5, c4 = (gid & 31) << 2;
  int r = mn[i];
  float4 rv = bf4_to_f4(*(const uint2*)(R + (size_t)r * 128 + c4));
  *(float4*)(o1 + (size_t)i * 128 + c4) = rv;
  *(float4*)(o2 + (size_t)i * 128 + c4) = *(const float4*)(X + (size_t)r * 128 + c4);
}

// ---------------------------------------------------------------------------
static void launch_gemm(const unsigned short* A1, const unsigned short* Wh1,
                        const unsigned short* Wl1, int k1,
                        const unsigned short* A2, const unsigned short* Wh2,
                        const unsigned short* Wl2, int k2,
                        const float* bias, int relu,
                        unsigned short* C, int m, int nrows, hipStream_t s) {
  int blocks = (nrows + 63) / 64;
  switch (m) {
    case 128:
      mfma_gemm_kernel<8><<<blocks, 256, 0, s>>>(A1, Wh1, Wl1, k1, A2, Wh2, Wl2, k2,
                                                 bias, relu, C, nrows);
      break;
    case 96:
      mfma_gemm_kernel<6><<<blocks, 256, 0, s>>>(A1, Wh1, Wl1, k1, A2, Wh2, Wl2, k2,
                                                 bias, relu, C, nrows);
      break;
    case 64:
      mfma_gemm_kernel<4><<<blocks, 256, 0, s>>>(A1, Wh1, Wl1, k1, A2, Wh2, Wl2, k2,
                                                 bias, relu, C, nrows);
      break;
  }
}

extern "C" void kernel_launch(void* const* d_in, const int* in_sizes, int n_in,
                              void* d_out, int out_size, void* d_ws, size_t ws_size,
                              hipStream_t stream) {
  const float* x = (const float*)d_in[0];
  const int* src = (const int*)d_in[1];
  const int* dst = (const int*)d_in[2];
  const float* ew = (const float*)d_in[3];
  const int* mn = (const int*)d_in[4];
  const float* token = (const float*)d_in[5];

  const float* W[20];
  for (int i = 0; i < 20; ++i) W[i] = (const float*)d_in[6 + i];
  const float* W_e2d = (const float*)d_in[26];
  const float* Wnp = (const float*)d_in[27];
  const float* bnp = (const float*)d_in[28];
  const float* ln_g = (const float*)d_in[29];
  const float* ln_b = (const float*)d_in[30];

  const int Nn = in_sizes[0] / 128;   // 50000
  const int E = in_sizes[1];          // 600000
  const int nmask = in_sizes[4];      // 10000
  const int nb = (Nn + SCAN_CHUNK - 1) / SCAN_CHUNK;  // 49

  // workspace layout (all bf16 activations)
  unsigned short* bufA = (unsigned short*)d_ws;            // N*128 bf16
  unsigned short* bufB = bufA + (size_t)Nn * 128;          // N*128 bf16
  unsigned short* pool16 = bufB + (size_t)Nn * 128;        // N*128 bf16
  unsigned short* neigh16 = pool16 + (size_t)Nn * 128;     // N*128 bf16
  int* deg = (int*)(neigh16 + (size_t)Nn * 128);           // N int
  int* cur = deg + Nn;                                     // N int
  int2* esw = (int2*)(cur + Nn);                           // E int2
  int* off = (int*)(esw + E);                              // N+1 int
  int* bsum = off + Nn + 1;                                // 64 int
  int* bbase = bsum + 64;                                  // 64 int
  float* WpP = (float*)(bbase + 64);                       // 64*64 f32
  float* WsP = WpP + 64 * 64;                              // 96*64 f32
  unsigned short* wplanes =
      (unsigned short*)(((uintptr_t)(WsP + 96 * 64) + 15) & ~(uintptr_t)15);

  // ---- fold encoder_to_decoder into dec0 weights (tiny) ----
  matmul_small_kernel<<<(64 * 64 + 255) / 256, 256, 0, stream>>>(W[10], W_e2d, WpP, 64, 64, 64);
  matmul_small_kernel<<<(96 * 64 + 255) / 256, 256, 0, stream>>>(W[12], W_e2d, WsP, 96, 64, 64);

  // ---- one-shot split of all GEMM weights into bf16 hi/lo planes ----
  const int msz[12] = {128 * 128, 96 * 128, 96 * 128, 96 * 96, 64 * 96, 64 * 96,
                       64 * 64,  96 * 64,  96 * 64,  96 * 96, 128 * 96, 128 * 96};
  const float* msrc[12] = {W[0], W[2], W[3], W[5], W[7], W[8],
                           WpP,  WsP,  W[13], W[15], W[17], W[18]};
  int mtot = 0;
  int moff[12];
  for (int i = 0; i < 12; ++i) { moff[i] = mtot; mtot += msz[i]; }
  unsigned short* wh_[12];
  unsigned short* wl_[12];
  SplitWArgs sa;
  for (int i = 0; i < 12; ++i) {
    wh_[i] = wplanes + moff[i];
    wl_[i] = wplanes + mtot + moff[i];
    sa.src[i] = msrc[i];
    sa.dh[i] = wh_[i];
    sa.dl[i] = wl_[i];
    sa.n[i] = msz[i];
  }
  {
    dim3 grid((128 * 128 / 4 + 255) / 256, 12);
    split_w_kernel<<<grid, 256, 0, stream>>>(sa);
  }

  // ---- CSR build (once; graph identical across layers) ----
  hipMemsetAsync(deg, 0, (size_t)Nn * 2 * sizeof(int), stream);  // deg + cur
  hist_kernel<<<(E + 255) / 256, 256, 0, stream>>>(dst, deg, E);
  blocksum_kernel<<<nb, 256, 0, stream>>>(deg, bsum, Nn);
  bscan_kernel<<<1, 64, 0, stream>>>(bsum, bbase, off + Nn, nb);
  chunkscan_kernel<<<nb, 256, 0, stream>>>(deg, bbase, off, Nn);
  scatter_kernel<<<(E + 255) / 256, 256, 0, stream>>>(src, dst, ew, off, cur, esw, E);

  // h = bf16(x); h[mask_nodes] = bf16(token)
  {
    int n4 = Nn * 128 / 4;
    copy_bf16_kernel<<<(n4 + 255) / 256, 256, 0, stream>>>((const float4*)x, (uint2*)bufA, n4);
    mask_scatter_kernel<<<(nmask * 32 + 255) / 256, 256, 0, stream>>>(mn, token, bufA, nmask);
  }

  // plane indices {wp, ws, wn} per layer
  auto run_sage = [&](int ip, int is, int in_, const float* bp, const float* b,
                      int din, int dout) {
    // p = relu(h @ Wp^T + bp)  -> bf16 pool
    launch_gemm(bufA, wh_[ip], wl_[ip], din, nullptr, nullptr, nullptr, 0,
                bp, 1, pool16, din, Nn, stream);
    // neigh = segment_max(p[src]*ew, dst), bf16; zero-degree rows -> 0
    int lanes = din >> 2;
    long long tot = (long long)Nn * lanes;
    int nblocks = (int)((tot + 255) / 256);
    neigh_csr_kernel<<<nblocks, 256, 0, stream>>>(pool16, off, esw, neigh16, din, lanes, Nn);
    // out = relu(h @ Ws^T + neigh @ Wn^T + b)  -> bf16
    launch_gemm(bufA, wh_[is], wl_[is], din, neigh16, wh_[in_], wl_[in_], din,
                b, 1, bufB, dout, Nn, stream);
    unsigned short* t = bufA; bufA = bufB; bufB = t;
  };

  // encoder
  run_sage(0, 1, 2, W[1], W[4], 128, 96);   // enc0
  run_sage(3, 4, 5, W[6], W[9], 96, 64);    // enc1

  // node_pred + layernorm -> n_scores (out section 3)
  float* out_r = (float*)d_out;
  float* out_x = out_r + (size_t)nmask * 128;
  float* out_ns = out_x + (size_t)nmask * 128;
  nodepred_ln_kernel<<<(Nn + 15) / 16, 256, 0, stream>>>(bufA, Wnp, bnp, ln_g, ln_b, out_ns, Nn);

  // decoder (e2d folded into dec0 weights)
  run_sage(6, 7, 8, W[11], W[14], 64, 96);     // dec0 (+e2d)
  run_sage(9, 10, 11, W[16], W[19], 96, 128);  // dec1

  // outputs 1 & 2
  gather_out_kernel<<<(nmask * 32 + 255) / 256, 256, 0, stream>>>(mn, bufA, x, out_r, out_x, nmask);
}